// Round 3
// baseline (429.830 us; speedup 1.0000x reference)
//
#include <hip/hip_runtime.h>
#include <math.h>
#include <float.h>

#define DIM 768
#define HEADS 12
#define HD 64
#define HIDDEN 3072
#define SEQ 2048
#define BATCH 2
#define NTOK (BATCH * SEQ)   // 4096
#define QKVC (3 * DIM)       // 2304
#define LN_EPS 1e-5f
#define SC2 0.1803368801111f  // 0.125 * log2(e)

typedef unsigned short u16;
typedef __attribute__((ext_vector_type(8))) __bf16 bf16x8;
typedef __attribute__((ext_vector_type(8))) unsigned short u16x8;
typedef __attribute__((ext_vector_type(4))) float f32x4;

__device__ __forceinline__ u16 f2bf(float f) {
    unsigned int u = __builtin_bit_cast(unsigned int, f);
    u += 0x7fffu + ((u >> 16) & 1u);
    return (u16)(u >> 16);
}

__device__ __forceinline__ f32x4 mfma16(u16x8 a, u16x8 b, f32x4 c) {
    return __builtin_amdgcn_mfma_f32_16x16x32_bf16(
        __builtin_bit_cast(bf16x8, a), __builtin_bit_cast(bf16x8, b), c, 0, 0, 0);
}

__device__ __forceinline__ void gl2lds16(const void* g, void* l) {
    __builtin_amdgcn_global_load_lds(
        (const __attribute__((address_space(1))) void*)g,
        (__attribute__((address_space(3))) void*)l, 16, 0, 0);
}

__device__ __forceinline__ float gelu_f(float v) {
    return 0.5f * v * (1.0f + erff(v * 0.70710678118654752f));
}

// ---------------- fp32 -> bf16 convert (weights) ----------------
__global__ __launch_bounds__(256) void cvt_bf16(const float* __restrict__ s,
                                                u16* __restrict__ d, int n) {
    int i = (blockIdx.x * 256 + threadIdx.x) * 4;
    if (i < n) {
        float4 v = *(const float4*)(s + i);
        ushort4 o;
        o.x = f2bf(v.x); o.y = f2bf(v.y); o.z = f2bf(v.z); o.w = f2bf(v.w);
        *(ushort4*)(d + i) = o;
    }
}

// ---------------- mask -> float bias ----------------
__global__ __launch_bounds__(256) void mbias_kernel(const int* __restrict__ mask,
                                                    float* __restrict__ mb) {
    int i = blockIdx.x * 256 + threadIdx.x;
    if (i < NTOK) mb[i] = (mask[i] == 1) ? -1e30f : 0.0f;
}

// ---------------- LayerNorm: fp32 in, bf16 out ----------------
__global__ __launch_bounds__(256) void ln_kernel(const float* __restrict__ x,
                                                 const float* __restrict__ g,
                                                 const float* __restrict__ bta,
                                                 u16* __restrict__ out) {
    int row = blockIdx.x;
    int t = threadIdx.x;
    const float* xr = x + (size_t)row * DIM;
    float v0 = xr[t], v1 = xr[t + 256], v2 = xr[t + 512];
    __shared__ float red[256];
    red[t] = v0 + v1 + v2;
    __syncthreads();
    for (int off = 128; off > 0; off >>= 1) {
        if (t < off) red[t] += red[t + off];
        __syncthreads();
    }
    float mean = red[0] * (1.0f / DIM);
    __syncthreads();
    float d0 = v0 - mean, d1 = v1 - mean, d2 = v2 - mean;
    red[t] = d0 * d0 + d1 * d1 + d2 * d2;
    __syncthreads();
    for (int off = 128; off > 0; off >>= 1) {
        if (t < off) red[t] += red[t + off];
        __syncthreads();
    }
    float rstd = rsqrtf(red[0] * (1.0f / DIM) + LN_EPS);
    u16* orow = out + (size_t)row * DIM;
    orow[t]       = f2bf(d0 * rstd * g[t]       + bta[t]);
    orow[t + 256] = f2bf(d1 * rstd * g[t + 256] + bta[t + 256]);
    orow[t + 512] = f2bf(d2 * rstd * g[t + 512] + bta[t + 512]);
}

// ---------------- repack: K -> [bh][key][d], V -> [bh][d][key] ----------------
__global__ __launch_bounds__(256) void repack_kv(const u16* __restrict__ qkv,
                                                 u16* __restrict__ kh,
                                                 u16* __restrict__ vth) {
    int s = blockIdx.x;          // 64-token tile
    int bh = blockIdx.y;
    int b = bh / HEADS, h = bh % HEADS;
    int t = threadIdx.x;
    __shared__ u16 Vl[64 * 72];
    const u16* base = qkv + ((size_t)(b * SEQ + s * 64)) * QKVC + h * HD;

    {   // K: coalesced copy
        int r = t >> 2, d0 = (t & 3) * 16;
        const u16* g = base + DIM + (size_t)r * QKVC + d0;
        u16* o = kh + (size_t)bh * (SEQ * HD) + (s * 64 + r) * HD + d0;
        *(uint4*)o = *(const uint4*)g;
        *(uint4*)(o + 8) = *(const uint4*)(g + 8);
    }
    {   // V: transpose via LDS (packed b32 writes)
        int vkey = (t & 31) * 2, vd0 = (t >> 5) * 8;
        const u16* g0 = base + 2 * DIM + (size_t)vkey * QKVC + vd0;
        u16x8 a = *(const u16x8*)g0;
        u16x8 c = *(const u16x8*)(g0 + QKVC);
#pragma unroll
        for (int j = 0; j < 8; ++j) {
            unsigned int pk = (unsigned int)a[j] | ((unsigned int)c[j] << 16);
            *(unsigned int*)(Vl + (vd0 + j) * 72 + vkey) = pk;
        }
    }
    __syncthreads();
    {   // write V^T coalesced
        int d = t >> 2, m0 = (t & 3) * 16;
        u16* o = vth + (size_t)bh * (SEQ * HD) + (size_t)d * SEQ + s * 64 + m0;
        *(uint4*)o = *(const uint4*)(Vl + d * 72 + m0);
        *(uint4*)(o + 8) = *(const uint4*)(Vl + d * 72 + m0 + 8);
    }
}

// ---------------- MFMA GEMM: C = A (MxK) * Bw^T (Bw is NxK), bf16 in ----------------
// EPI 0: bf16 out plain; 1: fp32 out +bias+resid; 2: bf16 out gelu(v+bias)
template <int BM, int BN, int EPI>
__global__ __launch_bounds__(256) void mgemm(const u16* __restrict__ A,
                                             const u16* __restrict__ Bw,
                                             void* __restrict__ Cout,
                                             int N, int K,
                                             const float* __restrict__ bias,
                                             const float* __restrict__ resid) {
    constexpr int WM = BM / 2, WN = BN / 2, NI = WM / 16, NJ = WN / 16;
    constexpr int ACALLS = (BM * 64) / 4096;   // 1KB per wave-call
    constexpr int BCALLS = (BN * 64) / 4096;
    __shared__ u16 As[BM * 32];
    __shared__ u16 Bs[BN * 32];
    int t = threadIdx.x;
    int w = t >> 6, lane = t & 63;
    int quad = lane >> 4, m16 = lane & 15;
    int row0 = blockIdx.y * BM, col0 = blockIdx.x * BN;
    int lrow = lane >> 2;          // 0..15 rows per call
    int lkb = (lane & 3) * 16;     // byte within 64B row

    f32x4 acc[NI][NJ] = {};

    for (int k0 = 0; k0 < K; k0 += 32) {
        __syncthreads();
#pragma unroll
        for (int c = 0; c < ACALLS; ++c) {
            int off = (w * ACALLS + c) * 1024;                 // bytes into tile
            int r = (off >> 6) + lrow;
            const u16* g = A + (size_t)(row0 + r) * K + k0 + (lkb >> 1);
            gl2lds16(g, As + (off >> 1));                      // wave-uniform LDS base
        }
#pragma unroll
        for (int c = 0; c < BCALLS; ++c) {
            int off = (w * BCALLS + c) * 1024;
            int r = (off >> 6) + lrow;
            const u16* g = Bw + (size_t)(col0 + r) * K + k0 + (lkb >> 1);
            gl2lds16(g, Bs + (off >> 1));
        }
        __syncthreads();
        u16x8 af[NI], bfj[NJ];
#pragma unroll
        for (int i = 0; i < NI; ++i)
            af[i] = *(const u16x8*)(As + ((w >> 1) * WM + 16 * i + m16) * 32 + quad * 8);
#pragma unroll
        for (int j = 0; j < NJ; ++j)
            bfj[j] = *(const u16x8*)(Bs + ((w & 1) * WN + 16 * j + m16) * 32 + quad * 8);
#pragma unroll
        for (int i = 0; i < NI; ++i)
#pragma unroll
            for (int j = 0; j < NJ; ++j)
                acc[i][j] = mfma16(af[i], bfj[j], acc[i][j]);
    }

    int wr0 = row0 + (w >> 1) * WM, wc0 = col0 + (w & 1) * WN;
#pragma unroll
    for (int i = 0; i < NI; ++i)
#pragma unroll
        for (int j = 0; j < NJ; ++j) {
            int ccol = wc0 + 16 * j + m16;
#pragma unroll
            for (int r = 0; r < 4; ++r) {
                int crow = wr0 + 16 * i + quad * 4 + r;
                float v = acc[i][j][r];
                if (EPI == 0) {
                    ((u16*)Cout)[(size_t)crow * N + ccol] = f2bf(v);
                } else if (EPI == 1) {
                    v += bias[ccol] + resid[(size_t)crow * N + ccol];
                    ((float*)Cout)[(size_t)crow * N + ccol] = v;
                } else {
                    v = gelu_f(v + bias[ccol]);
                    ((u16*)Cout)[(size_t)crow * N + ccol] = f2bf(v);
                }
            }
        }
}

// ---------------- Flash attention, bf16 MFMA, 128-key tiles ----------------
// block = 64 queries of one (b,h); 4 waves x 16 q-rows
__global__ __launch_bounds__(256) void attn_mfma(const u16* __restrict__ qkv,
                                                 const u16* __restrict__ kh,
                                                 const u16* __restrict__ vth,
                                                 const float* __restrict__ mb,
                                                 u16* __restrict__ y) {
    int qt = blockIdx.x, bh = blockIdx.y;
    int b = bh / HEADS, h = bh % HEADS;
    int t = threadIdx.x, w = t >> 6, lane = t & 63;
    int quad = lane >> 4, m16 = lane & 15;
    __shared__ u16 Ks[128 * 72];       // [key][d], 16B-aligned padded rows
    __shared__ u16 Vt[64 * 136];       // [d][key]
    __shared__ u16 Pw[4][16 * 136];    // per-wave P round-trip
    const u16* kbase = kh + (size_t)bh * (SEQ * HD);
    const u16* vbase = vth + (size_t)bh * (SEQ * HD);
    const float* mrow = mb + b * SEQ;

    int qrow = b * SEQ + qt * 64 + w * 16 + m16;
    const u16* qp = qkv + (size_t)qrow * QKVC + h * HD + quad * 8;
    u16x8 qf0 = *(const u16x8*)qp;
    u16x8 qf1 = *(const u16x8*)(qp + 32);

    float mrun[4], lrun[4];
    f32x4 O[4] = {};
#pragma unroll
    for (int r = 0; r < 4; ++r) { mrun[r] = -3e38f; lrun[r] = 0.f; }

    int kr = t >> 1, kd = (t & 1) * 32;   // K staging: 2 threads/row
    int vd = t >> 2, vm = (t & 3) * 32;   // V staging: 4 threads/row

    for (int k0 = 0; k0 < SEQ; k0 += 128) {
        // issue global loads before the barrier (no LDS touched)
        uint4 k4[4], v4[4];
        const u16* gk = kbase + (size_t)(k0 + kr) * HD + kd;
        const u16* gv = vbase + (size_t)vd * SEQ + k0 + vm;
#pragma unroll
        for (int c = 0; c < 4; ++c) k4[c] = *(const uint4*)(gk + c * 8);
#pragma unroll
        for (int c = 0; c < 4; ++c) v4[c] = *(const uint4*)(gv + c * 8);
        float kb[8];
#pragma unroll
        for (int nb = 0; nb < 8; ++nb) kb[nb] = mrow[k0 + m16 + 16 * nb];
        __syncthreads();
        u16* lk = Ks + kr * 72 + kd;
        u16* lv = Vt + vd * 136 + vm;
#pragma unroll
        for (int c = 0; c < 4; ++c) *(uint4*)(lk + c * 8) = k4[c];
#pragma unroll
        for (int c = 0; c < 4; ++c) *(uint4*)(lv + c * 8) = v4[c];
        __syncthreads();

        // S = Q*K^T in base-2 domain
        float sv[8][4];
#pragma unroll
        for (int nb = 0; nb < 8; ++nb) {
            const u16* krow = Ks + (m16 + 16 * nb) * 72 + quad * 8;
            f32x4 s = {0.f, 0.f, 0.f, 0.f};
            s = mfma16(qf0, *(const u16x8*)krow, s);
            s = mfma16(qf1, *(const u16x8*)(krow + 32), s);
#pragma unroll
            for (int r = 0; r < 4; ++r) sv[nb][r] = s[r] * SC2 + kb[nb];
        }
        float tmax[4];
#pragma unroll
        for (int r = 0; r < 4; ++r) {
            float m0 = fmaxf(fmaxf(sv[0][r], sv[1][r]), fmaxf(sv[2][r], sv[3][r]));
            float m1 = fmaxf(fmaxf(sv[4][r], sv[5][r]), fmaxf(sv[6][r], sv[7][r]));
            tmax[r] = fmaxf(m0, m1);
        }
#pragma unroll
        for (int off = 1; off < 16; off <<= 1)
#pragma unroll
            for (int r = 0; r < 4; ++r)
                tmax[r] = fmaxf(tmax[r], __shfl_xor(tmax[r], off));
        float al[4], ps[4];
#pragma unroll
        for (int r = 0; r < 4; ++r) {
            float mn = fmaxf(mrun[r], tmax[r]);
            al[r] = __builtin_amdgcn_exp2f(mrun[r] - mn);
            mrun[r] = mn;
            ps[r] = 0.f;
        }
#pragma unroll
        for (int nb = 0; nb < 8; ++nb)
#pragma unroll
            for (int r = 0; r < 4; ++r) {
                float p = __builtin_amdgcn_exp2f(sv[nb][r] - mrun[r]);
                sv[nb][r] = p;
                ps[r] += p;
            }
#pragma unroll
        for (int off = 1; off < 16; off <<= 1)
#pragma unroll
            for (int r = 0; r < 4; ++r)
                ps[r] += __shfl_xor(ps[r], off);
#pragma unroll
        for (int r = 0; r < 4; ++r) lrun[r] = lrun[r] * al[r] + ps[r];
#pragma unroll
        for (int nbd = 0; nbd < 4; ++nbd)
#pragma unroll
            for (int r = 0; r < 4; ++r) O[nbd][r] *= al[r];
        // P: D-layout -> LDS (wave-private, no barrier needed)
#pragma unroll
        for (int nb = 0; nb < 8; ++nb)
#pragma unroll
            for (int r = 0; r < 4; ++r)
                Pw[w][(quad * 4 + r) * 136 + m16 + 16 * nb] = f2bf(sv[nb][r]);
        u16x8 pf[4];
#pragma unroll
        for (int ks = 0; ks < 4; ++ks)
            pf[ks] = *(const u16x8*)(Pw[w] + m16 * 136 + ks * 32 + quad * 8);
#pragma unroll
        for (int nbd = 0; nbd < 4; ++nbd) {
            const u16* vr = Vt + (m16 + 16 * nbd) * 136 + quad * 8;
#pragma unroll
            for (int ks = 0; ks < 4; ++ks)
                O[nbd] = mfma16(pf[ks], *(const u16x8*)(vr + ks * 32), O[nbd]);
        }
    }
#pragma unroll
    for (int r = 0; r < 4; ++r) {
        float inv = 1.0f / lrun[r];
        int tok = b * SEQ + qt * 64 + w * 16 + quad * 4 + r;
        u16* yr = y + (size_t)tok * DIM + h * HD + m16;
#pragma unroll
        for (int nbd = 0; nbd < 4; ++nbd) yr[16 * nbd] = f2bf(O[nbd][r] * inv);
    }
}

extern "C" void kernel_launch(void* const* d_in, const int* in_sizes, int n_in,
                              void* d_out, int out_size, void* d_ws, size_t ws_size,
                              hipStream_t stream) {
    const float* x      = (const float*)d_in[0];
    const int*   mask   = (const int*)d_in[1];
    const float* ln1_g  = (const float*)d_in[2];
    const float* ln1_b  = (const float*)d_in[3];
    const float* qkv_w  = (const float*)d_in[4];
    const float* proj_w = (const float*)d_in[5];
    const float* proj_b = (const float*)d_in[6];
    const float* ln2_g  = (const float*)d_in[7];
    const float* ln2_b  = (const float*)d_in[8];
    const float* fc1_w  = (const float*)d_in[9];
    const float* fc1_b  = (const float*)d_in[10];
    const float* fc2_w  = (const float*)d_in[11];
    const float* fc2_b  = (const float*)d_in[12];
    float* out = (float*)d_out;

    // workspace layout (bytes)
    char* W = (char*)d_ws;
    u16*   wqkv  = (u16*)(W + 0);           // 2304x768   bf16
    u16*   wproj = (u16*)(W + 3538944);     // 768x768
    u16*   wfc1  = (u16*)(W + 4718592);     // 3072x768
    u16*   wfc2  = (u16*)(W + 9437184);     // 768x3072
    u16*   hbuf  = (u16*)(W + 14155776);    // 4096x768   bf16 (ln out, reused)
    float* x1    = (float*)(W + 20447232);  // 4096x768   fp32
    u16*   qkvb  = (u16*)(W + 33030144);    // 4096x2304  bf16
    u16*   ybuf  = (u16*)(W + 51904512);    // 4096x768   bf16
    u16*   a1    = (u16*)(W + 33030144);    // 4096x3072  bf16, aliases qkvb+ybuf (dead)
    float* mbuf  = (float*)(W + 58195968);  // 4096 fp32 mask bias
    u16*   khb   = (u16*)(W + 58212352);    // 24x2048x64 bf16
    u16*   vthb  = (u16*)(W + 64503808);    // 24x64x2048 bf16 (ends 70.8MB)

    cvt_bf16<<<1728, 256, 0, stream>>>(qkv_w, wqkv, 1769472);
    cvt_bf16<<<576,  256, 0, stream>>>(proj_w, wproj, 589824);
    cvt_bf16<<<2304, 256, 0, stream>>>(fc1_w, wfc1, 2359296);
    cvt_bf16<<<2304, 256, 0, stream>>>(fc2_w, wfc2, 2359296);
    mbias_kernel<<<16, 256, 0, stream>>>(mask, mbuf);

    ln_kernel<<<NTOK, 256, 0, stream>>>(x, ln1_g, ln1_b, hbuf);
    mgemm<128, 128, 0><<<dim3(QKVC / 128, NTOK / 128), 256, 0, stream>>>(
        hbuf, wqkv, qkvb, QKVC, DIM, nullptr, nullptr);
    repack_kv<<<dim3(SEQ / 64, BATCH * HEADS), 256, 0, stream>>>(qkvb, khb, vthb);
    attn_mfma<<<dim3(SEQ / 64, BATCH * HEADS), 256, 0, stream>>>(
        qkvb, khb, vthb, mbuf, ybuf);
    mgemm<128, 64, 1><<<dim3(DIM / 64, NTOK / 128), 256, 0, stream>>>(
        ybuf, wproj, x1, DIM, DIM, proj_b, x);
    ln_kernel<<<NTOK, 256, 0, stream>>>(x1, ln2_g, ln2_b, hbuf);
    mgemm<128, 128, 2><<<dim3(HIDDEN / 128, NTOK / 128), 256, 0, stream>>>(
        hbuf, wfc1, a1, HIDDEN, DIM, fc1_b, nullptr);
    mgemm<128, 64, 1><<<dim3(DIM / 64, NTOK / 128), 256, 0, stream>>>(
        a1, wfc2, out, DIM, HIDDEN, fc2_b, x1);
}

// Round 4
// 345.488 us; speedup vs baseline: 1.2441x; 1.2441x over previous
//
#include <hip/hip_runtime.h>
#include <math.h>
#include <float.h>

#define DIM 768
#define HEADS 12
#define HD 64
#define HIDDEN 3072
#define SEQ 2048
#define BATCH 2
#define NTOK (BATCH * SEQ)   // 4096
#define QKVC (3 * DIM)       // 2304
#define LN_EPS 1e-5f
#define SC2 0.1803368801111f  // 0.125 * log2(e)

typedef unsigned short u16;
typedef __attribute__((ext_vector_type(8))) __bf16 bf16x8;
typedef __attribute__((ext_vector_type(8))) unsigned short u16x8;
typedef __attribute__((ext_vector_type(4))) float f32x4;

__device__ __forceinline__ u16 f2bf(float f) {
    unsigned int u = __builtin_bit_cast(unsigned int, f);
    u += 0x7fffu + ((u >> 16) & 1u);
    return (u16)(u >> 16);
}

__device__ __forceinline__ f32x4 mfma16(u16x8 a, u16x8 b, f32x4 c) {
    return __builtin_amdgcn_mfma_f32_16x16x32_bf16(
        __builtin_bit_cast(bf16x8, a), __builtin_bit_cast(bf16x8, b), c, 0, 0, 0);
}

__device__ __forceinline__ void gl2lds16(const void* g, void* l) {
    __builtin_amdgcn_global_load_lds(
        (const __attribute__((address_space(1))) void*)g,
        (__attribute__((address_space(3))) void*)l, 16, 0, 0);
}

__device__ __forceinline__ float gelu_f(float v) {
    return 0.5f * v * (1.0f + erff(v * 0.70710678118654752f));
}

// ---------------- fp32 -> bf16 convert (weights) ----------------
__global__ __launch_bounds__(256) void cvt_bf16(const float* __restrict__ s,
                                                u16* __restrict__ d, int n) {
    int i = (blockIdx.x * 256 + threadIdx.x) * 4;
    if (i < n) {
        float4 v = *(const float4*)(s + i);
        ushort4 o;
        o.x = f2bf(v.x); o.y = f2bf(v.y); o.z = f2bf(v.z); o.w = f2bf(v.w);
        *(ushort4*)(d + i) = o;
    }
}

// ---------------- mask -> float bias ----------------
__global__ __launch_bounds__(256) void mbias_kernel(const int* __restrict__ mask,
                                                    float* __restrict__ mb) {
    int i = blockIdx.x * 256 + threadIdx.x;
    if (i < NTOK) mb[i] = (mask[i] == 1) ? -1e30f : 0.0f;
}

// ---------------- LayerNorm: fp32 in, bf16 out ----------------
__global__ __launch_bounds__(256) void ln_kernel(const float* __restrict__ x,
                                                 const float* __restrict__ g,
                                                 const float* __restrict__ bta,
                                                 u16* __restrict__ out) {
    int row = blockIdx.x;
    int t = threadIdx.x;
    const float* xr = x + (size_t)row * DIM;
    float v0 = xr[t], v1 = xr[t + 256], v2 = xr[t + 512];
    __shared__ float red[256];
    red[t] = v0 + v1 + v2;
    __syncthreads();
    for (int off = 128; off > 0; off >>= 1) {
        if (t < off) red[t] += red[t + off];
        __syncthreads();
    }
    float mean = red[0] * (1.0f / DIM);
    __syncthreads();
    float d0 = v0 - mean, d1 = v1 - mean, d2 = v2 - mean;
    red[t] = d0 * d0 + d1 * d1 + d2 * d2;
    __syncthreads();
    for (int off = 128; off > 0; off >>= 1) {
        if (t < off) red[t] += red[t + off];
        __syncthreads();
    }
    float rstd = rsqrtf(red[0] * (1.0f / DIM) + LN_EPS);
    u16* orow = out + (size_t)row * DIM;
    orow[t]       = f2bf(d0 * rstd * g[t]       + bta[t]);
    orow[t + 256] = f2bf(d1 * rstd * g[t + 256] + bta[t + 256]);
    orow[t + 512] = f2bf(d2 * rstd * g[t + 512] + bta[t + 512]);
}

// ---------------- repack: K -> [bh][key][d], V -> [bh][d][key] ----------------
__global__ __launch_bounds__(256) void repack_kv(const u16* __restrict__ qkv,
                                                 u16* __restrict__ kh,
                                                 u16* __restrict__ vth) {
    int s = blockIdx.x;          // 64-token tile
    int bh = blockIdx.y;
    int b = bh / HEADS, h = bh % HEADS;
    int t = threadIdx.x;
    __shared__ u16 Vl[64 * 72];
    const u16* base = qkv + ((size_t)(b * SEQ + s * 64)) * QKVC + h * HD;

    {   // K: coalesced copy
        int r = t >> 2, d0 = (t & 3) * 16;
        const u16* g = base + DIM + (size_t)r * QKVC + d0;
        u16* o = kh + (size_t)bh * (SEQ * HD) + (s * 64 + r) * HD + d0;
        *(uint4*)o = *(const uint4*)g;
        *(uint4*)(o + 8) = *(const uint4*)(g + 8);
    }
    {   // V: transpose via LDS (packed b32 writes)
        int vkey = (t & 31) * 2, vd0 = (t >> 5) * 8;
        const u16* g0 = base + 2 * DIM + (size_t)vkey * QKVC + vd0;
        u16x8 a = *(const u16x8*)g0;
        u16x8 c = *(const u16x8*)(g0 + QKVC);
#pragma unroll
        for (int j = 0; j < 8; ++j) {
            unsigned int pk = (unsigned int)a[j] | ((unsigned int)c[j] << 16);
            *(unsigned int*)(Vl + (vd0 + j) * 72 + vkey) = pk;
        }
    }
    __syncthreads();
    {   // write V^T coalesced
        int d = t >> 2, m0 = (t & 3) * 16;
        u16* o = vth + (size_t)bh * (SEQ * HD) + (size_t)d * SEQ + s * 64 + m0;
        *(uint4*)o = *(const uint4*)(Vl + d * 72 + m0);
        *(uint4*)(o + 8) = *(const uint4*)(Vl + d * 72 + m0 + 8);
    }
}

// ---------------- MFMA GEMM: C = A (MxK) * Bw^T (Bw is NxK), bf16 in ----------------
// EPI 0: bf16 out plain; 1: fp32 out +bias+resid; 2: bf16 out gelu(v+bias)
template <int BM, int BN, int EPI>
__global__ __launch_bounds__(256) void mgemm(const u16* __restrict__ A,
                                             const u16* __restrict__ Bw,
                                             void* __restrict__ Cout,
                                             int N, int K,
                                             const float* __restrict__ bias,
                                             const float* __restrict__ resid) {
    constexpr int WM = BM / 2, WN = BN / 2, NI = WM / 16, NJ = WN / 16;
    constexpr int ACALLS = (BM * 64) / 4096;   // 1KB per wave-call
    constexpr int BCALLS = (BN * 64) / 4096;
    __shared__ u16 As[BM * 32];
    __shared__ u16 Bs[BN * 32];
    int t = threadIdx.x;
    int w = t >> 6, lane = t & 63;
    int quad = lane >> 4, m16 = lane & 15;
    int row0 = blockIdx.y * BM, col0 = blockIdx.x * BN;
    int lrow = lane >> 2;          // 0..15 rows per call
    int lkb = (lane & 3) * 16;     // byte within 64B row

    f32x4 acc[NI][NJ] = {};

    for (int k0 = 0; k0 < K; k0 += 32) {
        __syncthreads();
#pragma unroll
        for (int c = 0; c < ACALLS; ++c) {
            int off = (w * ACALLS + c) * 1024;                 // bytes into tile
            int r = (off >> 6) + lrow;
            const u16* g = A + (size_t)(row0 + r) * K + k0 + (lkb >> 1);
            gl2lds16(g, As + (off >> 1));                      // wave-uniform LDS base
        }
#pragma unroll
        for (int c = 0; c < BCALLS; ++c) {
            int off = (w * BCALLS + c) * 1024;
            int r = (off >> 6) + lrow;
            const u16* g = Bw + (size_t)(col0 + r) * K + k0 + (lkb >> 1);
            gl2lds16(g, Bs + (off >> 1));
        }
        __syncthreads();
        u16x8 af[NI], bfj[NJ];
#pragma unroll
        for (int i = 0; i < NI; ++i)
            af[i] = *(const u16x8*)(As + ((w >> 1) * WM + 16 * i + m16) * 32 + quad * 8);
#pragma unroll
        for (int j = 0; j < NJ; ++j)
            bfj[j] = *(const u16x8*)(Bs + ((w & 1) * WN + 16 * j + m16) * 32 + quad * 8);
#pragma unroll
        for (int i = 0; i < NI; ++i)
#pragma unroll
            for (int j = 0; j < NJ; ++j)
                acc[i][j] = mfma16(af[i], bfj[j], acc[i][j]);
    }

    int wr0 = row0 + (w >> 1) * WM, wc0 = col0 + (w & 1) * WN;
#pragma unroll
    for (int i = 0; i < NI; ++i)
#pragma unroll
        for (int j = 0; j < NJ; ++j) {
            int ccol = wc0 + 16 * j + m16;
#pragma unroll
            for (int r = 0; r < 4; ++r) {
                int crow = wr0 + 16 * i + quad * 4 + r;
                float v = acc[i][j][r];
                if (EPI == 0) {
                    ((u16*)Cout)[(size_t)crow * N + ccol] = f2bf(v);
                } else if (EPI == 1) {
                    v += bias[ccol] + resid[(size_t)crow * N + ccol];
                    ((float*)Cout)[(size_t)crow * N + ccol] = v;
                } else {
                    v = gelu_f(v + bias[ccol]);
                    ((u16*)Cout)[(size_t)crow * N + ccol] = f2bf(v);
                }
            }
        }
}

// ---------------- Flash attention, bf16 MFMA, 128-key tiles ----------------
// block = 64 queries of one (b,h); 4 waves x 16 q-rows.
// K/V staged via global_load_lds with XOR chunk swizzle computed on the
// global pointer (LDS order is forced to lane order by the DMA).
//   Ks[r][slot]  : slot = chunk ^ (r & 7),  row stride 64 u16 (128 B)
//   Vt[d][slot]  : slot = chunk ^ (d & 15), row stride 128 u16 (256 B)
__global__ __launch_bounds__(256, 3) void attn_mfma(const u16* __restrict__ qkv,
                                                    const u16* __restrict__ kh,
                                                    const u16* __restrict__ vth,
                                                    const float* __restrict__ mb,
                                                    u16* __restrict__ y) {
    int qt = blockIdx.x, bh = blockIdx.y;
    int b = bh / HEADS, h = bh % HEADS;
    int t = threadIdx.x, w = t >> 6, lane = t & 63;
    int quad = lane >> 4, m16 = lane & 15;
    __shared__ u16 Ks[128 * 64];       // 16 KB
    __shared__ u16 Vt[64 * 128];       // 16 KB
    __shared__ u16 Pw[4][16 * 136];    // 17 KB, per-wave P round-trip
    const u16* kbase = kh + (size_t)bh * (SEQ * HD);
    const u16* vbase = vth + (size_t)bh * (SEQ * HD);
    const float* mrow = mb + b * SEQ;

    int qrow = b * SEQ + qt * 64 + w * 16 + m16;
    const u16* qp = qkv + (size_t)qrow * QKVC + h * HD + quad * 8;
    u16x8 qf0 = *(const u16x8*)qp;
    u16x8 qf1 = *(const u16x8*)(qp + 32);

    // staging lane decomposition
    int rloc = lane >> 3, kslot = lane & 7;   // K: 8 rows x 8 chunks per call
    int kchunk = kslot ^ rloc;                // row&7 == rloc within a call
    int dloc = lane >> 4, vslot = lane & 15;  // V: 4 rows x 16 chunks per call

    float mrun[4], lrun[4];
    f32x4 O[4] = {};
#pragma unroll
    for (int r = 0; r < 4; ++r) { mrun[r] = -3e38f; lrun[r] = 0.f; }

    int slo = quad ^ (m16 & 7);               // K read slots (hi = slo^4)

    for (int k0 = 0; k0 < SEQ; k0 += 128) {
        __syncthreads();
#pragma unroll
        for (int c = 0; c < 4; ++c) {         // K tile: 16 KB via 16 DMA calls
            int rb = (w * 4 + c) * 8;
            const u16* g = kbase + (size_t)(k0 + rb + rloc) * HD + kchunk * 8;
            gl2lds16(g, Ks + (w * 4 + c) * 512);
        }
#pragma unroll
        for (int c = 0; c < 4; ++c) {         // V tile
            int d = (w * 4 + c) * 4 + dloc;
            int chunk = vslot ^ (d & 15);
            const u16* g = vbase + (size_t)d * SEQ + k0 + chunk * 8;
            gl2lds16(g, Vt + (w * 4 + c) * 512);
        }
        float kb[8];
#pragma unroll
        for (int nb = 0; nb < 8; ++nb) kb[nb] = mrow[k0 + m16 + 16 * nb];
        __syncthreads();

        // S = Q*K^T in base-2 domain
        float sv[8][4];
#pragma unroll
        for (int nb = 0; nb < 8; ++nb) {
            const u16* krow = Ks + (m16 + 16 * nb) * 64;
            f32x4 s = {0.f, 0.f, 0.f, 0.f};
            s = mfma16(qf0, *(const u16x8*)(krow + slo * 8), s);
            s = mfma16(qf1, *(const u16x8*)(krow + (slo ^ 4) * 8), s);
#pragma unroll
            for (int r = 0; r < 4; ++r) sv[nb][r] = s[r] * SC2 + kb[nb];
        }
        float tmax[4];
#pragma unroll
        for (int r = 0; r < 4; ++r) {
            float a0 = fmaxf(fmaxf(sv[0][r], sv[1][r]), fmaxf(sv[2][r], sv[3][r]));
            float a1 = fmaxf(fmaxf(sv[4][r], sv[5][r]), fmaxf(sv[6][r], sv[7][r]));
            tmax[r] = fmaxf(a0, a1);
        }
#pragma unroll
        for (int off = 1; off < 16; off <<= 1)
#pragma unroll
            for (int r = 0; r < 4; ++r)
                tmax[r] = fmaxf(tmax[r], __shfl_xor(tmax[r], off));
        float al[4], ps[4];
#pragma unroll
        for (int r = 0; r < 4; ++r) {
            float mn = fmaxf(mrun[r], tmax[r]);
            al[r] = __builtin_amdgcn_exp2f(mrun[r] - mn);
            mrun[r] = mn;
            ps[r] = 0.f;
        }
#pragma unroll
        for (int nb = 0; nb < 8; ++nb)
#pragma unroll
            for (int r = 0; r < 4; ++r) {
                float p = __builtin_amdgcn_exp2f(sv[nb][r] - mrun[r]);
                sv[nb][r] = p;
                ps[r] += p;
            }
#pragma unroll
        for (int off = 1; off < 16; off <<= 1)
#pragma unroll
            for (int r = 0; r < 4; ++r)
                ps[r] += __shfl_xor(ps[r], off);
#pragma unroll
        for (int r = 0; r < 4; ++r) lrun[r] = lrun[r] * al[r] + ps[r];
#pragma unroll
        for (int nbd = 0; nbd < 4; ++nbd)
#pragma unroll
            for (int r = 0; r < 4; ++r) O[nbd][r] *= al[r];
        // P: D-layout -> LDS (wave-private, in-wave ordering suffices)
#pragma unroll
        for (int nb = 0; nb < 8; ++nb)
#pragma unroll
            for (int r = 0; r < 4; ++r)
                Pw[w][(quad * 4 + r) * 136 + m16 + 16 * nb] = f2bf(sv[nb][r]);
        u16x8 pf[4];
#pragma unroll
        for (int ks = 0; ks < 4; ++ks)
            pf[ks] = *(const u16x8*)(Pw[w] + m16 * 136 + ks * 32 + quad * 8);
#pragma unroll
        for (int nbd = 0; nbd < 4; ++nbd) {
            const u16* vrow = Vt + (nbd * 16 + m16) * 128;
#pragma unroll
            for (int ks = 0; ks < 4; ++ks) {
                int sl = (quad + 4 * ks) ^ m16;
                O[nbd] = mfma16(pf[ks], *(const u16x8*)(vrow + sl * 8), O[nbd]);
            }
        }
    }
#pragma unroll
    for (int r = 0; r < 4; ++r) {
        float inv = 1.0f / lrun[r];
        int tok = b * SEQ + qt * 64 + w * 16 + quad * 4 + r;
        u16* yr = y + (size_t)tok * DIM + h * HD + m16;
#pragma unroll
        for (int nbd = 0; nbd < 4; ++nbd) yr[16 * nbd] = f2bf(O[nbd][r] * inv);
    }
}

extern "C" void kernel_launch(void* const* d_in, const int* in_sizes, int n_in,
                              void* d_out, int out_size, void* d_ws, size_t ws_size,
                              hipStream_t stream) {
    const float* x      = (const float*)d_in[0];
    const int*   mask   = (const int*)d_in[1];
    const float* ln1_g  = (const float*)d_in[2];
    const float* ln1_b  = (const float*)d_in[3];
    const float* qkv_w  = (const float*)d_in[4];
    const float* proj_w = (const float*)d_in[5];
    const float* proj_b = (const float*)d_in[6];
    const float* ln2_g  = (const float*)d_in[7];
    const float* ln2_b  = (const float*)d_in[8];
    const float* fc1_w  = (const float*)d_in[9];
    const float* fc1_b  = (const float*)d_in[10];
    const float* fc2_w  = (const float*)d_in[11];
    const float* fc2_b  = (const float*)d_in[12];
    float* out = (float*)d_out;

    // workspace layout (bytes)
    char* W = (char*)d_ws;
    u16*   wqkv  = (u16*)(W + 0);           // 2304x768   bf16
    u16*   wproj = (u16*)(W + 3538944);     // 768x768
    u16*   wfc1  = (u16*)(W + 4718592);     // 3072x768
    u16*   wfc2  = (u16*)(W + 9437184);     // 768x3072
    u16*   hbuf  = (u16*)(W + 14155776);    // 4096x768   bf16 (ln out, reused)
    float* x1    = (float*)(W + 20447232);  // 4096x768   fp32
    u16*   qkvb  = (u16*)(W + 33030144);    // 4096x2304  bf16
    u16*   ybuf  = (u16*)(W + 51904512);    // 4096x768   bf16
    u16*   a1    = (u16*)(W + 33030144);    // 4096x3072  bf16, aliases qkvb+ybuf (dead)
    float* mbuf  = (float*)(W + 58195968);  // 4096 fp32 mask bias
    u16*   khb   = (u16*)(W + 58212352);    // 24x2048x64 bf16
    u16*   vthb  = (u16*)(W + 64503808);    // 24x64x2048 bf16 (ends 70.8MB)

    cvt_bf16<<<1728, 256, 0, stream>>>(qkv_w, wqkv, 1769472);
    cvt_bf16<<<576,  256, 0, stream>>>(proj_w, wproj, 589824);
    cvt_bf16<<<2304, 256, 0, stream>>>(fc1_w, wfc1, 2359296);
    cvt_bf16<<<2304, 256, 0, stream>>>(fc2_w, wfc2, 2359296);
    mbias_kernel<<<16, 256, 0, stream>>>(mask, mbuf);

    ln_kernel<<<NTOK, 256, 0, stream>>>(x, ln1_g, ln1_b, hbuf);
    mgemm<128, 128, 0><<<dim3(QKVC / 128, NTOK / 128), 256, 0, stream>>>(
        hbuf, wqkv, qkvb, QKVC, DIM, nullptr, nullptr);
    repack_kv<<<dim3(SEQ / 64, BATCH * HEADS), 256, 0, stream>>>(qkvb, khb, vthb);
    attn_mfma<<<dim3(SEQ / 64, BATCH * HEADS), 256, 0, stream>>>(
        qkvb, khb, vthb, mbuf, ybuf);
    mgemm<128, 64, 1><<<dim3(DIM / 64, NTOK / 128), 256, 0, stream>>>(
        ybuf, wproj, x1, DIM, DIM, proj_b, x);
    ln_kernel<<<NTOK, 256, 0, stream>>>(x1, ln2_g, ln2_b, hbuf);
    mgemm<128, 128, 2><<<dim3(HIDDEN / 128, NTOK / 128), 256, 0, stream>>>(
        hbuf, wfc1, a1, HIDDEN, DIM, fc1_b, nullptr);
    mgemm<128, 64, 1><<<dim3(DIM / 64, NTOK / 128), 256, 0, stream>>>(
        a1, wfc2, out, DIM, HIDDEN, fc2_b, x1);
}

// Round 5
// 317.376 us; speedup vs baseline: 1.3543x; 1.0886x over previous
//
#include <hip/hip_runtime.h>
#include <math.h>
#include <float.h>

#define DIM 768
#define HEADS 12
#define HD 64
#define HIDDEN 3072
#define SEQ 2048
#define BATCH 2
#define NTOK (BATCH * SEQ)   // 4096
#define QKVC (3 * DIM)       // 2304
#define LN_EPS 1e-5f
#define SC2 0.1803368801111f  // 0.125 * log2(e)

typedef unsigned short u16;
typedef __attribute__((ext_vector_type(8))) __bf16 bf16x8;
typedef __attribute__((ext_vector_type(8))) unsigned short u16x8;
typedef __attribute__((ext_vector_type(4))) float f32x4;

__device__ __forceinline__ u16 f2bf(float f) {
    unsigned int u = __builtin_bit_cast(unsigned int, f);
    u += 0x7fffu + ((u >> 16) & 1u);
    return (u16)(u >> 16);
}

__device__ __forceinline__ f32x4 mfma16(u16x8 a, u16x8 b, f32x4 c) {
    return __builtin_amdgcn_mfma_f32_16x16x32_bf16(
        __builtin_bit_cast(bf16x8, a), __builtin_bit_cast(bf16x8, b), c, 0, 0, 0);
}

__device__ __forceinline__ void gl2lds16(const void* g, void* l) {
    __builtin_amdgcn_global_load_lds(
        (const __attribute__((address_space(1))) void*)g,
        (__attribute__((address_space(3))) void*)l, 16, 0, 0);
}

__device__ __forceinline__ float gelu_f(float v) {
    return 0.5f * v * (1.0f + erff(v * 0.70710678118654752f));
}

// ---------------- fused fp32 -> bf16 convert of all 4 weight mats ----------------
// segment bounds: qkv 1769472 | proj +589824 | fc1 +2359296 | fc2 +2359296
__global__ __launch_bounds__(256) void cvt_all(const float* __restrict__ qkvw,
                                               const float* __restrict__ projw,
                                               const float* __restrict__ fc1w,
                                               const float* __restrict__ fc2w,
                                               u16* __restrict__ o_qkv,
                                               u16* __restrict__ o_proj,
                                               u16* __restrict__ o_fc1,
                                               u16* __restrict__ o_fc2) {
    long i = (long)(blockIdx.x * 256 + threadIdx.x) * 4;
    const float* s; u16* d; long off;
    if (i < 1769472)      { s = qkvw;  d = o_qkv;  off = i; }
    else if (i < 2359296) { s = projw; d = o_proj; off = i - 1769472; }
    else if (i < 4718592) { s = fc1w;  d = o_fc1;  off = i - 2359296; }
    else                  { s = fc2w;  d = o_fc2;  off = i - 4718592; }
    float4 v = *(const float4*)(s + off);
    ushort4 o;
    o.x = f2bf(v.x); o.y = f2bf(v.y); o.z = f2bf(v.z); o.w = f2bf(v.w);
    *(ushort4*)(d + off) = o;
}

// ---------------- mask scan: compacted positions + count + padded bias ----------
// one block per batch; pos[n] = compacted idx if unmasked else -1
__global__ __launch_bounds__(256) void scan_mask(const int* __restrict__ mask,
                                                 int* __restrict__ pos,
                                                 int* __restrict__ cnt,
                                                 float* __restrict__ cbias) {
    int b = blockIdx.x, t = threadIdx.x;
    const int* m = mask + b * SEQ;
    int v[8], s = 0;
#pragma unroll
    for (int j = 0; j < 8; ++j) { v[j] = (m[t * 8 + j] == 1) ? 0 : 1; s += v[j]; }
    __shared__ int red[256];
    __shared__ int tot;
    red[t] = s;
    __syncthreads();
    for (int off = 1; off < 256; off <<= 1) {
        int x = (t >= off) ? red[t - off] : 0;
        __syncthreads();
        red[t] += x;
        __syncthreads();
    }
    int base = red[t] - s;
    if (t == 255) tot = red[255];
    __syncthreads();
#pragma unroll
    for (int j = 0; j < 8; ++j) {
        pos[b * SEQ + t * 8 + j] = v[j] ? base : -1;
        base += v[j];
    }
    if (t == 0) cnt[b] = tot;
#pragma unroll
    for (int j = 0; j < 8; ++j) {
        int idx = t * 8 + j;
        cbias[b * SEQ + idx] = (idx < tot) ? 0.0f : -1e30f;
    }
}

// ---------------- LayerNorm: fp32 in, bf16 out ----------------
__global__ __launch_bounds__(256) void ln_kernel(const float* __restrict__ x,
                                                 const float* __restrict__ g,
                                                 const float* __restrict__ bta,
                                                 u16* __restrict__ out) {
    int row = blockIdx.x;
    int t = threadIdx.x;
    const float* xr = x + (size_t)row * DIM;
    float v0 = xr[t], v1 = xr[t + 256], v2 = xr[t + 512];
    __shared__ float red[256];
    red[t] = v0 + v1 + v2;
    __syncthreads();
    for (int off = 128; off > 0; off >>= 1) {
        if (t < off) red[t] += red[t + off];
        __syncthreads();
    }
    float mean = red[0] * (1.0f / DIM);
    __syncthreads();
    float d0 = v0 - mean, d1 = v1 - mean, d2 = v2 - mean;
    red[t] = d0 * d0 + d1 * d1 + d2 * d2;
    __syncthreads();
    for (int off = 128; off > 0; off >>= 1) {
        if (t < off) red[t] += red[t + off];
        __syncthreads();
    }
    float rstd = rsqrtf(red[0] * (1.0f / DIM) + LN_EPS);
    u16* orow = out + (size_t)row * DIM;
    orow[t]       = f2bf(d0 * rstd * g[t]       + bta[t]);
    orow[t + 256] = f2bf(d1 * rstd * g[t + 256] + bta[t + 256]);
    orow[t + 512] = f2bf(d2 * rstd * g[t + 512] + bta[t + 512]);
}

// ---------------- repack+compact: K -> [bh][cpos][d], V -> [bh][d][cpos] -------
__global__ __launch_bounds__(256) void repack_kv(const u16* __restrict__ qkv,
                                                 const int* __restrict__ pos,
                                                 u16* __restrict__ kh,
                                                 u16* __restrict__ vth) {
    int s = blockIdx.x;          // 64-token tile
    int bh = blockIdx.y;
    int b = bh / HEADS, h = bh % HEADS;
    int t = threadIdx.x;
    __shared__ u16 Vl[64 * 72];
    __shared__ int lpos[64];
    const u16* base = qkv + ((size_t)(b * SEQ + s * 64)) * QKVC + h * HD;
    if (t < 64) lpos[t] = pos[b * SEQ + s * 64 + t];
    {   // V: transpose via LDS (packed b32 writes), all 64 keys
        int vkey = (t & 31) * 2, vd0 = (t >> 5) * 8;
        const u16* g0 = base + 2 * DIM + (size_t)vkey * QKVC + vd0;
        u16x8 a = *(const u16x8*)g0;
        u16x8 c = *(const u16x8*)(g0 + QKVC);
#pragma unroll
        for (int j = 0; j < 8; ++j) {
            unsigned int pk = (unsigned int)a[j] | ((unsigned int)c[j] << 16);
            *(unsigned int*)(Vl + (vd0 + j) * 72 + vkey) = pk;
        }
    }
    __syncthreads();
    {   // K: compacted row scatter (destinations near-contiguous)
        int r = t >> 2, d0 = (t & 3) * 16;
        int p = lpos[r];
        if (p >= 0) {
            const u16* g = base + DIM + (size_t)r * QKVC + d0;
            u16* o = kh + (size_t)bh * (SEQ * HD) + (size_t)p * HD + d0;
            *(uint4*)o = *(const uint4*)g;
            *(uint4*)(o + 8) = *(const uint4*)(g + 8);
        }
    }
    {   // V^T: write only unmasked columns
        int d = t >> 2, m0 = (t & 3) * 16;
        u16* orow = vth + (size_t)bh * (HD * SEQ) + (size_t)d * SEQ;
#pragma unroll
        for (int j = 0; j < 16; ++j) {
            int p = lpos[m0 + j];
            if (p >= 0) orow[p] = Vl[d * 72 + m0 + j];
        }
    }
}

// ---------------- MFMA GEMM: C = A (MxK) * Bw^T (Bw is NxK), bf16 in ----------------
// EPI 0: bf16 out plain; 1: fp32 out +bias+resid; 2: bf16 out gelu(v+bias)
template <int BM, int BN, int EPI>
__global__ __launch_bounds__(256) void mgemm(const u16* __restrict__ A,
                                             const u16* __restrict__ Bw,
                                             void* __restrict__ Cout,
                                             int N, int K,
                                             const float* __restrict__ bias,
                                             const float* __restrict__ resid) {
    constexpr int WM = BM / 2, WN = BN / 2, NI = WM / 16, NJ = WN / 16;
    constexpr int ACALLS = (BM * 64) / 4096;   // 1KB per wave-call
    constexpr int BCALLS = (BN * 64) / 4096;
    __shared__ u16 As[BM * 32];
    __shared__ u16 Bs[BN * 32];
    int t = threadIdx.x;
    int w = t >> 6, lane = t & 63;
    int quad = lane >> 4, m16 = lane & 15;
    int row0 = blockIdx.y * BM, col0 = blockIdx.x * BN;
    int lrow = lane >> 2;          // 0..15 rows per call
    int lkb = (lane & 3) * 16;     // byte within 64B row

    f32x4 acc[NI][NJ] = {};

    for (int k0 = 0; k0 < K; k0 += 32) {
        __syncthreads();
#pragma unroll
        for (int c = 0; c < ACALLS; ++c) {
            int off = (w * ACALLS + c) * 1024;                 // bytes into tile
            int r = (off >> 6) + lrow;
            const u16* g = A + (size_t)(row0 + r) * K + k0 + (lkb >> 1);
            gl2lds16(g, As + (off >> 1));                      // wave-uniform LDS base
        }
#pragma unroll
        for (int c = 0; c < BCALLS; ++c) {
            int off = (w * BCALLS + c) * 1024;
            int r = (off >> 6) + lrow;
            const u16* g = Bw + (size_t)(col0 + r) * K + k0 + (lkb >> 1);
            gl2lds16(g, Bs + (off >> 1));
        }
        __syncthreads();
        u16x8 af[NI], bfj[NJ];
#pragma unroll
        for (int i = 0; i < NI; ++i)
            af[i] = *(const u16x8*)(As + ((w >> 1) * WM + 16 * i + m16) * 32 + quad * 8);
#pragma unroll
        for (int j = 0; j < NJ; ++j)
            bfj[j] = *(const u16x8*)(Bs + ((w & 1) * WN + 16 * j + m16) * 32 + quad * 8);
#pragma unroll
        for (int i = 0; i < NI; ++i)
#pragma unroll
            for (int j = 0; j < NJ; ++j)
                acc[i][j] = mfma16(af[i], bfj[j], acc[i][j]);
    }

    int wr0 = row0 + (w >> 1) * WM, wc0 = col0 + (w & 1) * WN;
#pragma unroll
    for (int i = 0; i < NI; ++i)
#pragma unroll
        for (int j = 0; j < NJ; ++j) {
            int ccol = wc0 + 16 * j + m16;
#pragma unroll
            for (int r = 0; r < 4; ++r) {
                int crow = wr0 + 16 * i + quad * 4 + r;
                float v = acc[i][j][r];
                if (EPI == 0) {
                    ((u16*)Cout)[(size_t)crow * N + ccol] = f2bf(v);
                } else if (EPI == 1) {
                    v += bias[ccol] + resid[(size_t)crow * N + ccol];
                    ((float*)Cout)[(size_t)crow * N + ccol] = v;
                } else {
                    v = gelu_f(v + bias[ccol]);
                    ((u16*)Cout)[(size_t)crow * N + ccol] = f2bf(v);
                }
            }
        }
}

// ---------------- Flash attention, bf16 MFMA, compacted 128-key tiles -----------
// block = 64 queries of one (b,h); 4 waves x 16 q-rows. Only ceil(cnt/128) tiles.
// K/V staged via global_load_lds with XOR chunk swizzle computed on the
// global pointer (LDS order is forced to lane order by the DMA).
//   Ks[r][slot]  : slot = chunk ^ (r & 7),  row stride 64 u16 (128 B)
//   Vt[d][slot]  : slot = chunk ^ (d & 15), row stride 128 u16 (256 B)
__global__ __launch_bounds__(256, 3) void attn_mfma(const u16* __restrict__ qkv,
                                                    const u16* __restrict__ kh,
                                                    const u16* __restrict__ vth,
                                                    const float* __restrict__ cbias,
                                                    const int* __restrict__ cnt,
                                                    u16* __restrict__ y) {
    int qt = blockIdx.x, bh = blockIdx.y;
    int b = bh / HEADS, h = bh % HEADS;
    int t = threadIdx.x, w = t >> 6, lane = t & 63;
    int quad = lane >> 4, m16 = lane & 15;
    __shared__ u16 Ks[128 * 64];       // 16 KB
    __shared__ u16 Vt[64 * 128];       // 16 KB
    __shared__ u16 Pw[4][16 * 136];    // 17 KB, per-wave P round-trip
    const u16* kbase = kh + (size_t)bh * (SEQ * HD);
    const u16* vbase = vth + (size_t)bh * (SEQ * HD);
    const float* mrow = cbias + b * SEQ;

    int qrow = b * SEQ + qt * 64 + w * 16 + m16;
    const u16* qp = qkv + (size_t)qrow * QKVC + h * HD + quad * 8;
    u16x8 qf0 = *(const u16x8*)qp;
    u16x8 qf1 = *(const u16x8*)(qp + 32);

    // staging lane decomposition
    int rloc = lane >> 3, kslot = lane & 7;   // K: 8 rows x 8 chunks per call
    int kchunk = kslot ^ rloc;                // row&7 == rloc within a call
    int dloc = lane >> 4, vslot = lane & 15;  // V: 4 rows x 16 chunks per call

    float mrun[4], lrun[4];
    f32x4 O[4] = {};
#pragma unroll
    for (int r = 0; r < 4; ++r) { mrun[r] = -3e38f; lrun[r] = 0.f; }

    int slo = quad ^ (m16 & 7);               // K read slots (hi = slo^4)

    int cntb = cnt[b];
    int ntile = (cntb + 127) >> 7;

    for (int kt = 0; kt < ntile; ++kt) {
        int k0 = kt << 7;
        __syncthreads();
#pragma unroll
        for (int c = 0; c < 4; ++c) {         // K tile: 16 KB via 16 DMA calls
            int rb = (w * 4 + c) * 8;
            const u16* g = kbase + (size_t)(k0 + rb + rloc) * HD + kchunk * 8;
            gl2lds16(g, Ks + (w * 4 + c) * 512);
        }
#pragma unroll
        for (int c = 0; c < 4; ++c) {         // V tile
            int d = (w * 4 + c) * 4 + dloc;
            int chunk = vslot ^ (d & 15);
            const u16* g = vbase + (size_t)d * SEQ + k0 + chunk * 8;
            gl2lds16(g, Vt + (w * 4 + c) * 512);
        }
        float kb[8];
#pragma unroll
        for (int nb = 0; nb < 8; ++nb) kb[nb] = mrow[k0 + m16 + 16 * nb];
        __syncthreads();

        // S = Q*K^T in base-2 domain
        float sv[8][4];
#pragma unroll
        for (int nb = 0; nb < 8; ++nb) {
            const u16* krow = Ks + (m16 + 16 * nb) * 64;
            f32x4 s = {0.f, 0.f, 0.f, 0.f};
            s = mfma16(qf0, *(const u16x8*)(krow + slo * 8), s);
            s = mfma16(qf1, *(const u16x8*)(krow + (slo ^ 4) * 8), s);
#pragma unroll
            for (int r = 0; r < 4; ++r) sv[nb][r] = s[r] * SC2 + kb[nb];
        }
        float tmax[4];
#pragma unroll
        for (int r = 0; r < 4; ++r) {
            float a0 = fmaxf(fmaxf(sv[0][r], sv[1][r]), fmaxf(sv[2][r], sv[3][r]));
            float a1 = fmaxf(fmaxf(sv[4][r], sv[5][r]), fmaxf(sv[6][r], sv[7][r]));
            tmax[r] = fmaxf(a0, a1);
        }
#pragma unroll
        for (int off = 1; off < 16; off <<= 1)
#pragma unroll
            for (int r = 0; r < 4; ++r)
                tmax[r] = fmaxf(tmax[r], __shfl_xor(tmax[r], off));
        float al[4], ps[4];
#pragma unroll
        for (int r = 0; r < 4; ++r) {
            float mn = fmaxf(mrun[r], tmax[r]);
            al[r] = __builtin_amdgcn_exp2f(mrun[r] - mn);
            mrun[r] = mn;
            ps[r] = 0.f;
        }
#pragma unroll
        for (int nb = 0; nb < 8; ++nb)
#pragma unroll
            for (int r = 0; r < 4; ++r) {
                float p = __builtin_amdgcn_exp2f(sv[nb][r] - mrun[r]);
                sv[nb][r] = p;
                ps[r] += p;
            }
#pragma unroll
        for (int off = 1; off < 16; off <<= 1)
#pragma unroll
            for (int r = 0; r < 4; ++r)
                ps[r] += __shfl_xor(ps[r], off);
#pragma unroll
        for (int r = 0; r < 4; ++r) lrun[r] = lrun[r] * al[r] + ps[r];
#pragma unroll
        for (int nbd = 0; nbd < 4; ++nbd)
#pragma unroll
            for (int r = 0; r < 4; ++r) O[nbd][r] *= al[r];
        // P: D-layout -> LDS (wave-private, in-wave ordering suffices)
#pragma unroll
        for (int nb = 0; nb < 8; ++nb)
#pragma unroll
            for (int r = 0; r < 4; ++r)
                Pw[w][(quad * 4 + r) * 136 + m16 + 16 * nb] = f2bf(sv[nb][r]);
        u16x8 pf[4];
#pragma unroll
        for (int ks = 0; ks < 4; ++ks)
            pf[ks] = *(const u16x8*)(Pw[w] + m16 * 136 + ks * 32 + quad * 8);
#pragma unroll
        for (int nbd = 0; nbd < 4; ++nbd) {
            const u16* vrow = Vt + (nbd * 16 + m16) * 128;
#pragma unroll
            for (int ks = 0; ks < 4; ++ks) {
                int sl = (quad + 4 * ks) ^ m16;
                O[nbd] = mfma16(pf[ks], *(const u16x8*)(vrow + sl * 8), O[nbd]);
            }
        }
    }
#pragma unroll
    for (int r = 0; r < 4; ++r) {
        float inv = 1.0f / lrun[r];
        int tok = b * SEQ + qt * 64 + w * 16 + quad * 4 + r;
        u16* yr = y + (size_t)tok * DIM + h * HD + m16;
#pragma unroll
        for (int nbd = 0; nbd < 4; ++nbd) yr[16 * nbd] = f2bf(O[nbd][r] * inv);
    }
}

extern "C" void kernel_launch(void* const* d_in, const int* in_sizes, int n_in,
                              void* d_out, int out_size, void* d_ws, size_t ws_size,
                              hipStream_t stream) {
    const float* x      = (const float*)d_in[0];
    const int*   mask   = (const int*)d_in[1];
    const float* ln1_g  = (const float*)d_in[2];
    const float* ln1_b  = (const float*)d_in[3];
    const float* qkv_w  = (const float*)d_in[4];
    const float* proj_w = (const float*)d_in[5];
    const float* proj_b = (const float*)d_in[6];
    const float* ln2_g  = (const float*)d_in[7];
    const float* ln2_b  = (const float*)d_in[8];
    const float* fc1_w  = (const float*)d_in[9];
    const float* fc1_b  = (const float*)d_in[10];
    const float* fc2_w  = (const float*)d_in[11];
    const float* fc2_b  = (const float*)d_in[12];
    float* out = (float*)d_out;

    // workspace layout (bytes)
    char* W = (char*)d_ws;
    u16*   wqkv  = (u16*)(W + 0);           // 2304x768   bf16
    u16*   wproj = (u16*)(W + 3538944);     // 768x768
    u16*   wfc1  = (u16*)(W + 4718592);     // 3072x768
    u16*   wfc2  = (u16*)(W + 9437184);     // 768x3072
    u16*   hbuf  = (u16*)(W + 14155776);    // 4096x768   bf16 (ln out, reused)
    float* x1    = (float*)(W + 20447232);  // 4096x768   fp32
    // scan outputs alias x1's head: all dead before proj GEMM writes x1
    float* cbias = (float*)(W + 20447232);  // 4096 fp32
    int*   posb  = (int*)(W + 20463616);    // 4096 int
    int*   cntb  = (int*)(W + 20480000);    // 2 int
    u16*   qkvb  = (u16*)(W + 33030144);    // 4096x2304  bf16
    u16*   ybuf  = (u16*)(W + 51904512);    // 4096x768   bf16
    u16*   a1    = (u16*)(W + 33030144);    // 4096x3072  bf16, aliases qkvb+ybuf (dead)
    u16*   khb   = (u16*)(W + 58212352);    // 24x2048x64 bf16 (compacted keys)
    u16*   vthb  = (u16*)(W + 64503808);    // 24x64x2048 bf16 (ends 70.8MB)

    cvt_all<<<6912, 256, 0, stream>>>(qkv_w, proj_w, fc1_w, fc2_w,
                                      wqkv, wproj, wfc1, wfc2);
    scan_mask<<<BATCH, 256, 0, stream>>>(mask, posb, cntb, cbias);

    ln_kernel<<<NTOK, 256, 0, stream>>>(x, ln1_g, ln1_b, hbuf);
    mgemm<128, 128, 0><<<dim3(QKVC / 128, NTOK / 128), 256, 0, stream>>>(
        hbuf, wqkv, qkvb, QKVC, DIM, nullptr, nullptr);
    repack_kv<<<dim3(SEQ / 64, BATCH * HEADS), 256, 0, stream>>>(qkvb, posb, khb, vthb);
    attn_mfma<<<dim3(SEQ / 64, BATCH * HEADS), 256, 0, stream>>>(
        qkvb, khb, vthb, cbias, cntb, ybuf);
    mgemm<128, 64, 1><<<dim3(DIM / 64, NTOK / 128), 256, 0, stream>>>(
        ybuf, wproj, x1, DIM, DIM, proj_b, x);
    ln_kernel<<<NTOK, 256, 0, stream>>>(x1, ln2_g, ln2_b, hbuf);
    mgemm<128, 128, 2><<<dim3(HIDDEN / 128, NTOK / 128), 256, 0, stream>>>(
        hbuf, wfc1, a1, HIDDEN, DIM, fc1_b, nullptr);
    mgemm<128, 64, 1><<<dim3(DIM / 64, NTOK / 128), 256, 0, stream>>>(
        a1, wfc2, out, DIM, HIDDEN, fc2_b, x1);
}

// Round 6
// 307.006 us; speedup vs baseline: 1.4001x; 1.0338x over previous
//
#include <hip/hip_runtime.h>
#include <math.h>
#include <float.h>

#define DIM 768
#define HEADS 12
#define HD 64
#define HIDDEN 3072
#define SEQ 2048
#define BATCH 2
#define NTOK (BATCH * SEQ)   // 4096
#define QKVC (3 * DIM)       // 2304
#define LN_EPS 1e-5f
#define SC2 0.1803368801111f  // 0.125 * log2(e)

typedef unsigned short u16;
typedef __attribute__((ext_vector_type(8))) __bf16 bf16x8;
typedef __attribute__((ext_vector_type(8))) unsigned short u16x8;
typedef __attribute__((ext_vector_type(4))) float f32x4;

__device__ __forceinline__ u16 f2bf(float f) {
    unsigned int u = __builtin_bit_cast(unsigned int, f);
    u += 0x7fffu + ((u >> 16) & 1u);
    return (u16)(u >> 16);
}

__device__ __forceinline__ f32x4 mfma16(u16x8 a, u16x8 b, f32x4 c) {
    return __builtin_amdgcn_mfma_f32_16x16x32_bf16(
        __builtin_bit_cast(bf16x8, a), __builtin_bit_cast(bf16x8, b), c, 0, 0, 0);
}

__device__ __forceinline__ void gl2lds16(const void* g, void* l) {
    __builtin_amdgcn_global_load_lds(
        (const __attribute__((address_space(1))) void*)g,
        (__attribute__((address_space(3))) void*)l, 16, 0, 0);
}

__device__ __forceinline__ float gelu_f(float v) {
    return 0.5f * v * (1.0f + erff(v * 0.70710678118654752f));
}

// ---------------- fused fp32 -> bf16 convert of all 4 weight mats ----------------
__global__ __launch_bounds__(256) void cvt_all(const float* __restrict__ qkvw,
                                               const float* __restrict__ projw,
                                               const float* __restrict__ fc1w,
                                               const float* __restrict__ fc2w,
                                               u16* __restrict__ o_qkv,
                                               u16* __restrict__ o_proj,
                                               u16* __restrict__ o_fc1,
                                               u16* __restrict__ o_fc2) {
    long i = (long)(blockIdx.x * 256 + threadIdx.x) * 4;
    const float* s; u16* d; long off;
    if (i < 1769472)      { s = qkvw;  d = o_qkv;  off = i; }
    else if (i < 2359296) { s = projw; d = o_proj; off = i - 1769472; }
    else if (i < 4718592) { s = fc1w;  d = o_fc1;  off = i - 2359296; }
    else                  { s = fc2w;  d = o_fc2;  off = i - 4718592; }
    float4 v = *(const float4*)(s + off);
    ushort4 o;
    o.x = f2bf(v.x); o.y = f2bf(v.y); o.z = f2bf(v.z); o.w = f2bf(v.w);
    *(ushort4*)(d + off) = o;
}

// ---------------- mask scan: compacted positions + count + padded bias ----------
__global__ __launch_bounds__(256) void scan_mask(const int* __restrict__ mask,
                                                 int* __restrict__ pos,
                                                 int* __restrict__ cnt,
                                                 float* __restrict__ cbias) {
    int b = blockIdx.x, t = threadIdx.x;
    const int* m = mask + b * SEQ;
    int v[8], s = 0;
#pragma unroll
    for (int j = 0; j < 8; ++j) { v[j] = (m[t * 8 + j] == 1) ? 0 : 1; s += v[j]; }
    __shared__ int red[256];
    __shared__ int tot;
    red[t] = s;
    __syncthreads();
    for (int off = 1; off < 256; off <<= 1) {
        int x = (t >= off) ? red[t - off] : 0;
        __syncthreads();
        red[t] += x;
        __syncthreads();
    }
    int base = red[t] - s;
    if (t == 255) tot = red[255];
    __syncthreads();
#pragma unroll
    for (int j = 0; j < 8; ++j) {
        pos[b * SEQ + t * 8 + j] = v[j] ? base : -1;
        base += v[j];
    }
    if (t == 0) cnt[b] = tot;
#pragma unroll
    for (int j = 0; j < 8; ++j) {
        int idx = t * 8 + j;
        cbias[b * SEQ + idx] = (idx < tot) ? 0.0f : -1e30f;
    }
}

// ---------------- LayerNorm: fp32 in, bf16 out ----------------
__global__ __launch_bounds__(256) void ln_kernel(const float* __restrict__ x,
                                                 const float* __restrict__ g,
                                                 const float* __restrict__ bta,
                                                 u16* __restrict__ out) {
    int row = blockIdx.x;
    int t = threadIdx.x;
    const float* xr = x + (size_t)row * DIM;
    float v0 = xr[t], v1 = xr[t + 256], v2 = xr[t + 512];
    __shared__ float red[256];
    red[t] = v0 + v1 + v2;
    __syncthreads();
    for (int off = 128; off > 0; off >>= 1) {
        if (t < off) red[t] += red[t + off];
        __syncthreads();
    }
    float mean = red[0] * (1.0f / DIM);
    __syncthreads();
    float d0 = v0 - mean, d1 = v1 - mean, d2 = v2 - mean;
    red[t] = d0 * d0 + d1 * d1 + d2 * d2;
    __syncthreads();
    for (int off = 128; off > 0; off >>= 1) {
        if (t < off) red[t] += red[t + off];
        __syncthreads();
    }
    float rstd = rsqrtf(red[0] * (1.0f / DIM) + LN_EPS);
    u16* orow = out + (size_t)row * DIM;
    orow[t]       = f2bf(d0 * rstd * g[t]       + bta[t]);
    orow[t + 256] = f2bf(d1 * rstd * g[t + 256] + bta[t + 256]);
    orow[t + 512] = f2bf(d2 * rstd * g[t + 512] + bta[t + 512]);
}

// ---------------- repack+compact: K -> [bh][cpos][d], V -> [bh][d][cpos] -------
__global__ __launch_bounds__(256) void repack_kv(const u16* __restrict__ qkv,
                                                 const int* __restrict__ pos,
                                                 u16* __restrict__ kh,
                                                 u16* __restrict__ vth) {
    int s = blockIdx.x;          // 64-token tile
    int bh = blockIdx.y;
    int b = bh / HEADS, h = bh % HEADS;
    int t = threadIdx.x;
    __shared__ u16 Vl[64 * 72];
    __shared__ int lpos[64];
    const u16* base = qkv + ((size_t)(b * SEQ + s * 64)) * QKVC + h * HD;
    if (t < 64) lpos[t] = pos[b * SEQ + s * 64 + t];
    {   // V: transpose via LDS (packed b32 writes), all 64 keys
        int vkey = (t & 31) * 2, vd0 = (t >> 5) * 8;
        const u16* g0 = base + 2 * DIM + (size_t)vkey * QKVC + vd0;
        u16x8 a = *(const u16x8*)g0;
        u16x8 c = *(const u16x8*)(g0 + QKVC);
#pragma unroll
        for (int j = 0; j < 8; ++j) {
            unsigned int pk = (unsigned int)a[j] | ((unsigned int)c[j] << 16);
            *(unsigned int*)(Vl + (vd0 + j) * 72 + vkey) = pk;
        }
    }
    __syncthreads();
    {   // K: compacted row scatter
        int r = t >> 2, d0 = (t & 3) * 16;
        int p = lpos[r];
        if (p >= 0) {
            const u16* g = base + DIM + (size_t)r * QKVC + d0;
            u16* o = kh + (size_t)bh * (SEQ * HD) + (size_t)p * HD + d0;
            *(uint4*)o = *(const uint4*)g;
            *(uint4*)(o + 8) = *(const uint4*)(g + 8);
        }
    }
    {   // V^T: write only unmasked columns
        int d = t >> 2, m0 = (t & 3) * 16;
        u16* orow = vth + (size_t)bh * (HD * SEQ) + (size_t)d * SEQ;
#pragma unroll
        for (int j = 0; j < 16; ++j) {
            int p = lpos[m0 + j];
            if (p >= 0) orow[p] = Vl[d * 72 + m0 + j];
        }
    }
}

// ---------------- MFMA GEMM: C = A (MxK) * Bw^T (Bw is NxK), bf16 in ----------------
// EPI 0: bf16 plain; 1: fp32 +bias+resid; 2: bf16 gelu(v+bias); 3: fp32 raw partial
// blockIdx.z selects K-half (klen per z) and dst (z ? Cout2 : Cout).
// XCD swizzle: same output-row-panel -> same flat%8 -> same XCD L2.
template <int BM, int BN, int EPI>
__global__ __launch_bounds__(256) void mgemm(const u16* __restrict__ A,
                                             const u16* __restrict__ Bw,
                                             void* __restrict__ Cout,
                                             void* __restrict__ Cout2,
                                             int N, int klen,
                                             const float* __restrict__ bias,
                                             const float* __restrict__ resid) {
    constexpr int WM = BM / 2, WN = BN / 2, NI = WM / 16, NJ = WN / 16;
    constexpr int ACALLS = (BM * 64) / 4096;   // 1KB per wave-call
    constexpr int BCALLS = (BN * 64) / 4096;
    __shared__ u16 As[BM * 32];
    __shared__ u16 Bs[BN * 32];
    int t = threadIdx.x;
    int w = t >> 6, lane = t & 63;
    int quad = lane >> 4, m16 = lane & 15;
    int gx = gridDim.x;
    int flat = blockIdx.y * gx + blockIdx.x;
    int bx = (flat >> 3) % gx;
    int by = (flat & 7) + 8 * ((flat >> 3) / gx);
    int K = klen * gridDim.z;                  // full K (row stride of A/B)
    int kbeg = blockIdx.z * klen, kend = kbeg + klen;
    int row0 = by * BM, col0 = bx * BN;
    int lrow = lane >> 2;          // 0..15 rows per call
    int lkb = (lane & 3) * 16;     // byte within 64B row

    f32x4 acc[NI][NJ] = {};

    for (int k0 = kbeg; k0 < kend; k0 += 32) {
        __syncthreads();
#pragma unroll
        for (int c = 0; c < ACALLS; ++c) {
            int off = (w * ACALLS + c) * 1024;                 // bytes into tile
            int r = (off >> 6) + lrow;
            const u16* g = A + (size_t)(row0 + r) * K + k0 + (lkb >> 1);
            gl2lds16(g, As + (off >> 1));                      // wave-uniform LDS base
        }
#pragma unroll
        for (int c = 0; c < BCALLS; ++c) {
            int off = (w * BCALLS + c) * 1024;
            int r = (off >> 6) + lrow;
            const u16* g = Bw + (size_t)(col0 + r) * K + k0 + (lkb >> 1);
            gl2lds16(g, Bs + (off >> 1));
        }
        __syncthreads();
        u16x8 af[NI], bfj[NJ];
#pragma unroll
        for (int i = 0; i < NI; ++i)
            af[i] = *(const u16x8*)(As + ((w >> 1) * WM + 16 * i + m16) * 32 + quad * 8);
#pragma unroll
        for (int j = 0; j < NJ; ++j)
            bfj[j] = *(const u16x8*)(Bs + ((w & 1) * WN + 16 * j + m16) * 32 + quad * 8);
#pragma unroll
        for (int i = 0; i < NI; ++i)
#pragma unroll
            for (int j = 0; j < NJ; ++j)
                acc[i][j] = mfma16(af[i], bfj[j], acc[i][j]);
    }

    void* dst = blockIdx.z ? Cout2 : Cout;
    int wr0 = row0 + (w >> 1) * WM, wc0 = col0 + (w & 1) * WN;
#pragma unroll
    for (int i = 0; i < NI; ++i)
#pragma unroll
        for (int j = 0; j < NJ; ++j) {
            int ccol = wc0 + 16 * j + m16;
#pragma unroll
            for (int r = 0; r < 4; ++r) {
                int crow = wr0 + 16 * i + quad * 4 + r;
                float v = acc[i][j][r];
                if (EPI == 0) {
                    ((u16*)dst)[(size_t)crow * N + ccol] = f2bf(v);
                } else if (EPI == 1) {
                    v += bias[ccol] + resid[(size_t)crow * N + ccol];
                    ((float*)dst)[(size_t)crow * N + ccol] = v;
                } else if (EPI == 2) {
                    v = gelu_f(v + bias[ccol]);
                    ((u16*)dst)[(size_t)crow * N + ccol] = f2bf(v);
                } else {
                    ((float*)dst)[(size_t)crow * N + ccol] = v;
                }
            }
        }
}

// ---------------- split-K merge: out = out + part + bias + resid ----------------
__global__ __launch_bounds__(256) void merge_kernel(float* __restrict__ out,
                                                    const float* __restrict__ part,
                                                    const float* __restrict__ bias,
                                                    const float* __restrict__ resid) {
    int i = (blockIdx.x * 256 + threadIdx.x) * 4;
    int col = i % DIM;
    float4 o = *(const float4*)(out + i);
    float4 p = *(const float4*)(part + i);
    float4 rr = *(const float4*)(resid + i);
    float4 bb = *(const float4*)(bias + col);
    o.x += p.x + rr.x + bb.x; o.y += p.y + rr.y + bb.y;
    o.z += p.z + rr.z + bb.z; o.w += p.w + rr.w + bb.w;
    *(float4*)(out + i) = o;
}

// ---------------- Flash attention, bf16 MFMA, compacted 128-key tiles -----------
// block = 64 queries of one (b,h); swizzled so same bh -> same XCD.
__global__ __launch_bounds__(256, 3) void attn_mfma(const u16* __restrict__ qkv,
                                                    const u16* __restrict__ kh,
                                                    const u16* __restrict__ vth,
                                                    const float* __restrict__ cbias,
                                                    const int* __restrict__ cnt,
                                                    u16* __restrict__ y) {
    int gx = gridDim.x;
    int flat = blockIdx.y * gx + blockIdx.x;
    int qt = (flat >> 3) % gx;
    int bh = (flat & 7) + 8 * ((flat >> 3) / gx);
    int b = bh / HEADS, h = bh % HEADS;
    int t = threadIdx.x, w = t >> 6, lane = t & 63;
    int quad = lane >> 4, m16 = lane & 15;
    __shared__ u16 Ks[128 * 64];       // 16 KB
    __shared__ u16 Vt[64 * 128];       // 16 KB
    __shared__ u16 Pw[4][16 * 136];    // 17 KB, per-wave P round-trip
    const u16* kbase = kh + (size_t)bh * (SEQ * HD);
    const u16* vbase = vth + (size_t)bh * (SEQ * HD);
    const float* mrow = cbias + b * SEQ;

    int qrow = b * SEQ + qt * 64 + w * 16 + m16;
    const u16* qp = qkv + (size_t)qrow * QKVC + h * HD + quad * 8;
    u16x8 qf0 = *(const u16x8*)qp;
    u16x8 qf1 = *(const u16x8*)(qp + 32);

    int rloc = lane >> 3, kslot = lane & 7;   // K: 8 rows x 8 chunks per call
    int kchunk = kslot ^ rloc;
    int dloc = lane >> 4, vslot = lane & 15;  // V: 4 rows x 16 chunks per call

    float mrun[4], lrun[4];
    f32x4 O[4] = {};
#pragma unroll
    for (int r = 0; r < 4; ++r) { mrun[r] = -3e38f; lrun[r] = 0.f; }

    int slo = quad ^ (m16 & 7);               // K read slots (hi = slo^4)

    int cntb = cnt[b];
    int ntile = (cntb + 127) >> 7;

    for (int kt = 0; kt < ntile; ++kt) {
        int k0 = kt << 7;
        __syncthreads();
#pragma unroll
        for (int c = 0; c < 4; ++c) {         // K tile: 16 KB via 16 DMA calls
            int rb = (w * 4 + c) * 8;
            const u16* g = kbase + (size_t)(k0 + rb + rloc) * HD + kchunk * 8;
            gl2lds16(g, Ks + (w * 4 + c) * 512);
        }
#pragma unroll
        for (int c = 0; c < 4; ++c) {         // V tile
            int d = (w * 4 + c) * 4 + dloc;
            int chunk = vslot ^ (d & 15);
            const u16* g = vbase + (size_t)d * SEQ + k0 + chunk * 8;
            gl2lds16(g, Vt + (w * 4 + c) * 512);
        }
        float kb[8];
#pragma unroll
        for (int nb = 0; nb < 8; ++nb) kb[nb] = mrow[k0 + m16 + 16 * nb];
        __syncthreads();

        float sv[8][4];
#pragma unroll
        for (int nb = 0; nb < 8; ++nb) {
            const u16* krow = Ks + (m16 + 16 * nb) * 64;
            f32x4 s = {0.f, 0.f, 0.f, 0.f};
            s = mfma16(qf0, *(const u16x8*)(krow + slo * 8), s);
            s = mfma16(qf1, *(const u16x8*)(krow + (slo ^ 4) * 8), s);
#pragma unroll
            for (int r = 0; r < 4; ++r) sv[nb][r] = s[r] * SC2 + kb[nb];
        }
        float tmax[4];
#pragma unroll
        for (int r = 0; r < 4; ++r) {
            float a0 = fmaxf(fmaxf(sv[0][r], sv[1][r]), fmaxf(sv[2][r], sv[3][r]));
            float a1 = fmaxf(fmaxf(sv[4][r], sv[5][r]), fmaxf(sv[6][r], sv[7][r]));
            tmax[r] = fmaxf(a0, a1);
        }
#pragma unroll
        for (int off = 1; off < 16; off <<= 1)
#pragma unroll
            for (int r = 0; r < 4; ++r)
                tmax[r] = fmaxf(tmax[r], __shfl_xor(tmax[r], off));
        float al[4], ps[4];
#pragma unroll
        for (int r = 0; r < 4; ++r) {
            float mn = fmaxf(mrun[r], tmax[r]);
            al[r] = __builtin_amdgcn_exp2f(mrun[r] - mn);
            mrun[r] = mn;
            ps[r] = 0.f;
        }
#pragma unroll
        for (int nb = 0; nb < 8; ++nb)
#pragma unroll
            for (int r = 0; r < 4; ++r) {
                float p = __builtin_amdgcn_exp2f(sv[nb][r] - mrun[r]);
                sv[nb][r] = p;
                ps[r] += p;
            }
#pragma unroll
        for (int off = 1; off < 16; off <<= 1)
#pragma unroll
            for (int r = 0; r < 4; ++r)
                ps[r] += __shfl_xor(ps[r], off);
#pragma unroll
        for (int r = 0; r < 4; ++r) lrun[r] = lrun[r] * al[r] + ps[r];
#pragma unroll
        for (int nbd = 0; nbd < 4; ++nbd)
#pragma unroll
            for (int r = 0; r < 4; ++r) O[nbd][r] *= al[r];
#pragma unroll
        for (int nb = 0; nb < 8; ++nb)
#pragma unroll
            for (int r = 0; r < 4; ++r)
                Pw[w][(quad * 4 + r) * 136 + m16 + 16 * nb] = f2bf(sv[nb][r]);
        u16x8 pf[4];
#pragma unroll
        for (int ks = 0; ks < 4; ++ks)
            pf[ks] = *(const u16x8*)(Pw[w] + m16 * 136 + ks * 32 + quad * 8);
#pragma unroll
        for (int nbd = 0; nbd < 4; ++nbd) {
            const u16* vrow = Vt + (nbd * 16 + m16) * 128;
#pragma unroll
            for (int ks = 0; ks < 4; ++ks) {
                int sl = (quad + 4 * ks) ^ m16;
                O[nbd] = mfma16(pf[ks], *(const u16x8*)(vrow + sl * 8), O[nbd]);
            }
        }
    }
#pragma unroll
    for (int r = 0; r < 4; ++r) {
        float inv = 1.0f / lrun[r];
        int tok = b * SEQ + qt * 64 + w * 16 + quad * 4 + r;
        u16* yr = y + (size_t)tok * DIM + h * HD + m16;
#pragma unroll
        for (int nbd = 0; nbd < 4; ++nbd) yr[16 * nbd] = f2bf(O[nbd][r] * inv);
    }
}

extern "C" void kernel_launch(void* const* d_in, const int* in_sizes, int n_in,
                              void* d_out, int out_size, void* d_ws, size_t ws_size,
                              hipStream_t stream) {
    const float* x      = (const float*)d_in[0];
    const int*   mask   = (const int*)d_in[1];
    const float* ln1_g  = (const float*)d_in[2];
    const float* ln1_b  = (const float*)d_in[3];
    const float* qkv_w  = (const float*)d_in[4];
    const float* proj_w = (const float*)d_in[5];
    const float* proj_b = (const float*)d_in[6];
    const float* ln2_g  = (const float*)d_in[7];
    const float* ln2_b  = (const float*)d_in[8];
    const float* fc1_w  = (const float*)d_in[9];
    const float* fc1_b  = (const float*)d_in[10];
    const float* fc2_w  = (const float*)d_in[11];
    const float* fc2_b  = (const float*)d_in[12];
    float* out = (float*)d_out;

    // workspace layout (bytes)
    char* W = (char*)d_ws;
    u16*   wqkv  = (u16*)(W + 0);           // 2304x768   bf16
    u16*   wproj = (u16*)(W + 3538944);     // 768x768
    u16*   wfc1  = (u16*)(W + 4718592);     // 3072x768
    u16*   wfc2  = (u16*)(W + 9437184);     // 768x3072
    u16*   hbuf  = (u16*)(W + 14155776);    // 4096x768   bf16 (ln out, reused)
    float* x1    = (float*)(W + 20447232);  // 4096x768   fp32
    // scan outputs alias x1's head: all dead before proj GEMM writes x1
    float* cbias = (float*)(W + 20447232);  // 4096 fp32
    int*   posb  = (int*)(W + 20463616);    // 4096 int
    int*   cntb  = (int*)(W + 20480000);    // 2 int
    u16*   qkvb  = (u16*)(W + 33030144);    // 4096x2304  bf16
    u16*   ybuf  = (u16*)(W + 51904512);    // 4096x768   bf16
    u16*   a1    = (u16*)(W + 33030144);    // 4096x3072  bf16, aliases qkvb+ybuf (dead)
    u16*   khb   = (u16*)(W + 58212352);    // 24x2048x64 bf16 (compacted keys)
    u16*   vthb  = (u16*)(W + 64503808);    // 24x64x2048 bf16 (ends 70.8MB)
    float* pp    = (float*)(W + 58212352);  // 4096x768 fp32 split-K partial
                                            // (reuses khb+vthb, dead after attn)

    cvt_all<<<6912, 256, 0, stream>>>(qkv_w, proj_w, fc1_w, fc2_w,
                                      wqkv, wproj, wfc1, wfc2);
    scan_mask<<<BATCH, 256, 0, stream>>>(mask, posb, cntb, cbias);

    ln_kernel<<<NTOK, 256, 0, stream>>>(x, ln1_g, ln1_b, hbuf);
    mgemm<128, 128, 0><<<dim3(QKVC / 128, NTOK / 128), 256, 0, stream>>>(
        hbuf, wqkv, qkvb, nullptr, QKVC, DIM, nullptr, nullptr);
    repack_kv<<<dim3(SEQ / 64, BATCH * HEADS), 256, 0, stream>>>(qkvb, posb, khb, vthb);
    attn_mfma<<<dim3(SEQ / 64, BATCH * HEADS), 256, 0, stream>>>(
        qkvb, khb, vthb, cbias, cntb, ybuf);
    mgemm<128, 64, 1><<<dim3(DIM / 64, NTOK / 128), 256, 0, stream>>>(
        ybuf, wproj, x1, nullptr, DIM, DIM, proj_b, x);
    ln_kernel<<<NTOK, 256, 0, stream>>>(x1, ln2_g, ln2_b, hbuf);
    mgemm<128, 128, 2><<<dim3(HIDDEN / 128, NTOK / 128), 256, 0, stream>>>(
        hbuf, wfc1, a1, nullptr, HIDDEN, DIM, fc1_b, nullptr);
    // FC2 split-K=2: z=0 -> pp, z=1 -> out (raw partials), then merge
    mgemm<128, 64, 3><<<dim3(DIM / 64, NTOK / 128, 2), 256, 0, stream>>>(
        a1, wfc2, pp, out, DIM, HIDDEN / 2, nullptr, nullptr);
    merge_kernel<<<NTOK * DIM / 1024, 256, 0, stream>>>(out, pp, fc2_b, x1);
}

// Round 7
// 291.362 us; speedup vs baseline: 1.4752x; 1.0537x over previous
//
#include <hip/hip_runtime.h>
#include <math.h>
#include <float.h>

#define DIM 768
#define HEADS 12
#define HD 64
#define HIDDEN 3072
#define SEQ 2048
#define BATCH 2
#define NTOK (BATCH * SEQ)   // 4096
#define QKVC (3 * DIM)       // 2304
#define LN_EPS 1e-5f
#define SC2 0.1803368801111f  // 0.125 * log2(e)

typedef unsigned short u16;
typedef __attribute__((ext_vector_type(8))) __bf16 bf16x8;
typedef __attribute__((ext_vector_type(8))) unsigned short u16x8;
typedef __attribute__((ext_vector_type(4))) float f32x4;

__device__ __forceinline__ u16 f2bf(float f) {
    unsigned int u = __builtin_bit_cast(unsigned int, f);
    u += 0x7fffu + ((u >> 16) & 1u);
    return (u16)(u >> 16);
}

__device__ __forceinline__ f32x4 mfma16(u16x8 a, u16x8 b, f32x4 c) {
    return __builtin_amdgcn_mfma_f32_16x16x32_bf16(
        __builtin_bit_cast(bf16x8, a), __builtin_bit_cast(bf16x8, b), c, 0, 0, 0);
}

__device__ __forceinline__ void gl2lds16(const void* g, void* l) {
    __builtin_amdgcn_global_load_lds(
        (const __attribute__((address_space(1))) void*)g,
        (__attribute__((address_space(3))) void*)l, 16, 0, 0);
}

__device__ __forceinline__ float gelu_f(float v) {
    return 0.5f * v * (1.0f + erff(v * 0.70710678118654752f));
}

// ------- fused: fp32->bf16 weight convert (blocks 0..6911) + mask scan (6912..6913)
__global__ __launch_bounds__(256) void cvt_all(const float* __restrict__ qkvw,
                                               const float* __restrict__ projw,
                                               const float* __restrict__ fc1w,
                                               const float* __restrict__ fc2w,
                                               u16* __restrict__ o_qkv,
                                               u16* __restrict__ o_proj,
                                               u16* __restrict__ o_fc1,
                                               u16* __restrict__ o_fc2,
                                               const int* __restrict__ mask,
                                               int* __restrict__ pos,
                                               int* __restrict__ cnt) {
    if (blockIdx.x >= 6912) {   // ---- mask scan, one block per batch ----
        int b = blockIdx.x - 6912, t = threadIdx.x;
        const int* m = mask + b * SEQ;
        int v[8], s = 0;
#pragma unroll
        for (int j = 0; j < 8; ++j) { v[j] = (m[t * 8 + j] == 1) ? 0 : 1; s += v[j]; }
        __shared__ int red[256];
        red[t] = s;
        __syncthreads();
        for (int off = 1; off < 256; off <<= 1) {
            int x = (t >= off) ? red[t - off] : 0;
            __syncthreads();
            red[t] += x;
            __syncthreads();
        }
        int base = red[t] - s;
#pragma unroll
        for (int j = 0; j < 8; ++j) {
            pos[b * SEQ + t * 8 + j] = v[j] ? base : -1;
            base += v[j];
        }
        if (t == 255) cnt[b] = red[255];
        return;
    }
    long i = (long)(blockIdx.x * 256 + threadIdx.x) * 4;
    const float* s; u16* d; long off;
    if (i < 1769472)      { s = qkvw;  d = o_qkv;  off = i; }
    else if (i < 2359296) { s = projw; d = o_proj; off = i - 1769472; }
    else if (i < 4718592) { s = fc1w;  d = o_fc1;  off = i - 2359296; }
    else                  { s = fc2w;  d = o_fc2;  off = i - 4718592; }
    float4 v = *(const float4*)(s + off);
    ushort4 o;
    o.x = f2bf(v.x); o.y = f2bf(v.y); o.z = f2bf(v.z); o.w = f2bf(v.w);
    *(ushort4*)(d + off) = o;
}

// ---------------- LayerNorm: fp32 in, bf16 out ----------------
__global__ __launch_bounds__(256) void ln_kernel(const float* __restrict__ x,
                                                 const float* __restrict__ g,
                                                 const float* __restrict__ bta,
                                                 u16* __restrict__ out) {
    int row = blockIdx.x;
    int t = threadIdx.x;
    const float* xr = x + (size_t)row * DIM;
    float v0 = xr[t], v1 = xr[t + 256], v2 = xr[t + 512];
    __shared__ float red[256];
    red[t] = v0 + v1 + v2;
    __syncthreads();
    for (int off = 128; off > 0; off >>= 1) {
        if (t < off) red[t] += red[t + off];
        __syncthreads();
    }
    float mean = red[0] * (1.0f / DIM);
    __syncthreads();
    float d0 = v0 - mean, d1 = v1 - mean, d2 = v2 - mean;
    red[t] = d0 * d0 + d1 * d1 + d2 * d2;
    __syncthreads();
    for (int off = 128; off > 0; off >>= 1) {
        if (t < off) red[t] += red[t + off];
        __syncthreads();
    }
    float rstd = rsqrtf(red[0] * (1.0f / DIM) + LN_EPS);
    u16* orow = out + (size_t)row * DIM;
    orow[t]       = f2bf(d0 * rstd * g[t]       + bta[t]);
    orow[t + 256] = f2bf(d1 * rstd * g[t + 256] + bta[t + 256]);
    orow[t + 512] = f2bf(d2 * rstd * g[t + 512] + bta[t + 512]);
}

// ---------------- repack+compact: K -> [bh][cpos][d], V -> [bh][d][cpos] -------
__global__ __launch_bounds__(256) void repack_kv(const u16* __restrict__ qkv,
                                                 const int* __restrict__ pos,
                                                 u16* __restrict__ kh,
                                                 u16* __restrict__ vth) {
    int s = blockIdx.x;          // 64-token tile
    int bh = blockIdx.y;
    int b = bh / HEADS, h = bh % HEADS;
    int t = threadIdx.x;
    __shared__ u16 Vl[64 * 72];
    __shared__ int lpos[64];
    const u16* base = qkv + ((size_t)(b * SEQ + s * 64)) * QKVC + h * HD;
    if (t < 64) lpos[t] = pos[b * SEQ + s * 64 + t];
    {   // V: transpose via LDS (packed b32 writes), all 64 keys
        int vkey = (t & 31) * 2, vd0 = (t >> 5) * 8;
        const u16* g0 = base + 2 * DIM + (size_t)vkey * QKVC + vd0;
        u16x8 a = *(const u16x8*)g0;
        u16x8 c = *(const u16x8*)(g0 + QKVC);
#pragma unroll
        for (int j = 0; j < 8; ++j) {
            unsigned int pk = (unsigned int)a[j] | ((unsigned int)c[j] << 16);
            *(unsigned int*)(Vl + (vd0 + j) * 72 + vkey) = pk;
        }
    }
    __syncthreads();
    {   // K: compacted row scatter
        int r = t >> 2, d0 = (t & 3) * 16;
        int p = lpos[r];
        if (p >= 0) {
            const u16* g = base + DIM + (size_t)r * QKVC + d0;
            u16* o = kh + (size_t)bh * (SEQ * HD) + (size_t)p * HD + d0;
            *(uint4*)o = *(const uint4*)g;
            *(uint4*)(o + 8) = *(const uint4*)(g + 8);
        }
    }
    {   // V^T: write only unmasked columns
        int d = t >> 2, m0 = (t & 3) * 16;
        u16* orow = vth + (size_t)bh * (HD * SEQ) + (size_t)d * SEQ;
#pragma unroll
        for (int j = 0; j < 16; ++j) {
            int p = lpos[m0 + j];
            if (p >= 0) orow[p] = Vl[d * 72 + m0 + j];
        }
    }
}

// ---------------- MFMA GEMM: C = A (MxK) * Bw^T (Bw is NxK), bf16 in ----------------
// EPI 0: bf16 plain; 1: fp32 +bias+resid; 2: bf16 gelu(v+bias); 3: fp32 raw partial
// blockIdx.z selects K-slice (klen per z) and dst (z ? Cout2 : Cout).
template <int BM, int BN, int EPI>
__global__ __launch_bounds__(256) void mgemm(const u16* __restrict__ A,
                                             const u16* __restrict__ Bw,
                                             void* __restrict__ Cout,
                                             void* __restrict__ Cout2,
                                             int N, int klen,
                                             const float* __restrict__ bias,
                                             const float* __restrict__ resid) {
    constexpr int WM = BM / 2, WN = BN / 2, NI = WM / 16, NJ = WN / 16;
    constexpr int ACALLS = (BM * 64) / 4096;   // 1KB per wave-call
    constexpr int BCALLS = (BN * 64) / 4096;
    __shared__ u16 As[BM * 32];
    __shared__ u16 Bs[BN * 32];
    int t = threadIdx.x;
    int w = t >> 6, lane = t & 63;
    int quad = lane >> 4, m16 = lane & 15;
    int K = klen * gridDim.z;                  // full K (row stride of A/B)
    int kbeg = blockIdx.z * klen, kend = kbeg + klen;
    int row0 = blockIdx.y * BM, col0 = blockIdx.x * BN;
    int lrow = lane >> 2;          // 0..15 rows per call
    int lkb = (lane & 3) * 16;     // byte within 64B row

    f32x4 acc[NI][NJ] = {};

    for (int k0 = kbeg; k0 < kend; k0 += 32) {
        __syncthreads();
#pragma unroll
        for (int c = 0; c < ACALLS; ++c) {
            int off = (w * ACALLS + c) * 1024;                 // bytes into tile
            int r = (off >> 6) + lrow;
            const u16* g = A + (size_t)(row0 + r) * K + k0 + (lkb >> 1);
            gl2lds16(g, As + (off >> 1));                      // wave-uniform LDS base
        }
#pragma unroll
        for (int c = 0; c < BCALLS; ++c) {
            int off = (w * BCALLS + c) * 1024;
            int r = (off >> 6) + lrow;
            const u16* g = Bw + (size_t)(col0 + r) * K + k0 + (lkb >> 1);
            gl2lds16(g, Bs + (off >> 1));
        }
        __syncthreads();
        u16x8 af[NI], bfj[NJ];
#pragma unroll
        for (int i = 0; i < NI; ++i)
            af[i] = *(const u16x8*)(As + ((w >> 1) * WM + 16 * i + m16) * 32 + quad * 8);
#pragma unroll
        for (int j = 0; j < NJ; ++j)
            bfj[j] = *(const u16x8*)(Bs + ((w & 1) * WN + 16 * j + m16) * 32 + quad * 8);
#pragma unroll
        for (int i = 0; i < NI; ++i)
#pragma unroll
            for (int j = 0; j < NJ; ++j)
                acc[i][j] = mfma16(af[i], bfj[j], acc[i][j]);
    }

    void* dst = blockIdx.z ? Cout2 : Cout;
    int wr0 = row0 + (w >> 1) * WM, wc0 = col0 + (w & 1) * WN;
#pragma unroll
    for (int i = 0; i < NI; ++i)
#pragma unroll
        for (int j = 0; j < NJ; ++j) {
            int ccol = wc0 + 16 * j + m16;
#pragma unroll
            for (int r = 0; r < 4; ++r) {
                int crow = wr0 + 16 * i + quad * 4 + r;
                float v = acc[i][j][r];
                if (EPI == 0) {
                    ((u16*)dst)[(size_t)crow * N + ccol] = f2bf(v);
                } else if (EPI == 1) {
                    v += bias[ccol] + resid[(size_t)crow * N + ccol];
                    ((float*)dst)[(size_t)crow * N + ccol] = v;
                } else if (EPI == 2) {
                    v = gelu_f(v + bias[ccol]);
                    ((u16*)dst)[(size_t)crow * N + ccol] = f2bf(v);
                } else {
                    ((float*)dst)[(size_t)crow * N + ccol] = v;
                }
            }
        }
}

// ---------------- split-K merge: out = out + part + bias + resid ----------------
__global__ __launch_bounds__(256) void merge_kernel(float* __restrict__ out,
                                                    const float* __restrict__ part,
                                                    const float* __restrict__ bias,
                                                    const float* __restrict__ resid) {
    int i = (blockIdx.x * 256 + threadIdx.x) * 4;
    int col = i % DIM;
    float4 o = *(const float4*)(out + i);
    float4 p = *(const float4*)(part + i);
    float4 rr = *(const float4*)(resid + i);
    float4 bb = *(const float4*)(bias + col);
    o.x += p.x + rr.x + bb.x; o.y += p.y + rr.y + bb.y;
    o.z += p.z + rr.z + bb.z; o.w += p.w + rr.w + bb.w;
    *(float4*)(out + i) = o;
}

// ---------------- Flash attention, bf16 MFMA, compacted 128-key tiles -----------
// Fixed-base softmax (M0=0): scores provably < 2^127 in base-2 domain, so no
// running max, no rescale; per-lane sums deferred to one end-of-kernel tree.
__global__ __launch_bounds__(256, 3) void attn_mfma(const u16* __restrict__ qkv,
                                                    const u16* __restrict__ kh,
                                                    const u16* __restrict__ vth,
                                                    const int* __restrict__ cnt,
                                                    u16* __restrict__ y) {
    int gx = gridDim.x;
    int flat = blockIdx.y * gx + blockIdx.x;
    int qt = (flat >> 3) % gx;
    int bh = (flat & 7) + 8 * ((flat >> 3) / gx);
    int b = bh / HEADS, h = bh % HEADS;
    int t = threadIdx.x, w = t >> 6, lane = t & 63;
    int quad = lane >> 4, m16 = lane & 15;
    __shared__ u16 Ks[128 * 64];       // 16 KB
    __shared__ u16 Vt[64 * 128];       // 16 KB
    __shared__ u16 Pw[4][16 * 136];    // 17 KB, per-wave P round-trip
    const u16* kbase = kh + (size_t)bh * (SEQ * HD);
    const u16* vbase = vth + (size_t)bh * (SEQ * HD);

    int qrow = b * SEQ + qt * 64 + w * 16 + m16;
    const u16* qp = qkv + (size_t)qrow * QKVC + h * HD + quad * 8;
    u16x8 qf0 = *(const u16x8*)qp;
    u16x8 qf1 = *(const u16x8*)(qp + 32);

    int rloc = lane >> 3, kslot = lane & 7;   // K: 8 rows x 8 chunks per call
    int kchunk = kslot ^ rloc;
    int dloc = lane >> 4, vslot = lane & 15;  // V: 4 rows x 16 chunks per call

    float lsum[4] = {0.f, 0.f, 0.f, 0.f};
    f32x4 O[4] = {};

    int slo = quad ^ (m16 & 7);               // K read slots (hi = slo^4)

    int cntb = cnt[b];
    int ntile = (cntb + 127) >> 7;

    for (int kt = 0; kt < ntile; ++kt) {
        int k0 = kt << 7;
        __syncthreads();
#pragma unroll
        for (int c = 0; c < 4; ++c) {         // K tile: 16 KB via 16 DMA calls
            int rb = (w * 4 + c) * 8;
            const u16* g = kbase + (size_t)(k0 + rb + rloc) * HD + kchunk * 8;
            gl2lds16(g, Ks + (w * 4 + c) * 512);
        }
#pragma unroll
        for (int c = 0; c < 4; ++c) {         // V tile
            int d = (w * 4 + c) * 4 + dloc;
            int chunk = vslot ^ (d & 15);
            const u16* g = vbase + (size_t)d * SEQ + k0 + chunk * 8;
            gl2lds16(g, Vt + (w * 4 + c) * 512);
        }
        float kb[8];
#pragma unroll
        for (int nb = 0; nb < 8; ++nb)
            kb[nb] = (k0 + m16 + 16 * nb < cntb) ? 0.0f : -1e30f;
        __syncthreads();

        // P = exp2(S*SC2 + kb), accumulated per-lane (no max, no rescale)
#pragma unroll
        for (int nb = 0; nb < 8; ++nb) {
            const u16* krow = Ks + (m16 + 16 * nb) * 64;
            f32x4 s = {0.f, 0.f, 0.f, 0.f};
            s = mfma16(qf0, *(const u16x8*)(krow + slo * 8), s);
            s = mfma16(qf1, *(const u16x8*)(krow + (slo ^ 4) * 8), s);
#pragma unroll
            for (int r = 0; r < 4; ++r) {
                float p = __builtin_amdgcn_exp2f(s[r] * SC2 + kb[nb]);
                lsum[r] += p;
                Pw[w][(quad * 4 + r) * 136 + m16 + 16 * nb] = f2bf(p);
            }
        }
        u16x8 pf[4];
#pragma unroll
        for (int ks = 0; ks < 4; ++ks)
            pf[ks] = *(const u16x8*)(Pw[w] + m16 * 136 + ks * 32 + quad * 8);
#pragma unroll
        for (int nbd = 0; nbd < 4; ++nbd) {
            const u16* vrow = Vt + (nbd * 16 + m16) * 128;
#pragma unroll
            for (int ks = 0; ks < 4; ++ks) {
                int sl = (quad + 4 * ks) ^ m16;
                O[nbd] = mfma16(pf[ks], *(const u16x8*)(vrow + sl * 8), O[nbd]);
            }
        }
    }
    // one sum-tree at the end (16-lane groups share rows)
#pragma unroll
    for (int off = 1; off < 16; off <<= 1)
#pragma unroll
        for (int r = 0; r < 4; ++r)
            lsum[r] += __shfl_xor(lsum[r], off);
#pragma unroll
    for (int r = 0; r < 4; ++r) {
        float inv = 1.0f / lsum[r];
        int tok = b * SEQ + qt * 64 + w * 16 + quad * 4 + r;
        u16* yr = y + (size_t)tok * DIM + h * HD + m16;
#pragma unroll
        for (int nbd = 0; nbd < 4; ++nbd) yr[16 * nbd] = f2bf(O[nbd][r] * inv);
    }
}

extern "C" void kernel_launch(void* const* d_in, const int* in_sizes, int n_in,
                              void* d_out, int out_size, void* d_ws, size_t ws_size,
                              hipStream_t stream) {
    const float* x      = (const float*)d_in[0];
    const int*   mask   = (const int*)d_in[1];
    const float* ln1_g  = (const float*)d_in[2];
    const float* ln1_b  = (const float*)d_in[3];
    const float* qkv_w  = (const float*)d_in[4];
    const float* proj_w = (const float*)d_in[5];
    const float* proj_b = (const float*)d_in[6];
    const float* ln2_g  = (const float*)d_in[7];
    const float* ln2_b  = (const float*)d_in[8];
    const float* fc1_w  = (const float*)d_in[9];
    const float* fc1_b  = (const float*)d_in[10];
    const float* fc2_w  = (const float*)d_in[11];
    const float* fc2_b  = (const float*)d_in[12];
    float* out = (float*)d_out;

    // workspace layout (bytes)
    char* W = (char*)d_ws;
    u16*   wqkv  = (u16*)(W + 0);           // 2304x768   bf16
    u16*   wproj = (u16*)(W + 3538944);     // 768x768
    u16*   wfc1  = (u16*)(W + 4718592);     // 3072x768
    u16*   wfc2  = (u16*)(W + 9437184);     // 768x3072
    u16*   hbuf  = (u16*)(W + 14155776);    // 4096x768   bf16 (ln out, reused)
    float* x1    = (float*)(W + 20447232);  // 4096x768   fp32
    // scan outputs alias x1's head: dead before proj GEMM writes x1
    int*   posb  = (int*)(W + 20463616);    // 4096 int
    int*   cntb  = (int*)(W + 20480000);    // 2 int
    u16*   qkvb  = (u16*)(W + 33030144);    // 4096x2304  bf16
    u16*   ybuf  = (u16*)(W + 51904512);    // 4096x768   bf16
    u16*   a1    = (u16*)(W + 33030144);    // 4096x3072  bf16, aliases qkvb+ybuf (dead)
    u16*   khb   = (u16*)(W + 58212352);    // 24x2048x64 bf16 (compacted keys)
    u16*   vthb  = (u16*)(W + 64503808);    // 24x64x2048 bf16 (ends 70.8MB)
    float* pp    = (float*)(W + 58212352);  // 4096x768 fp32 split-K partial
                                            // (reuses khb+vthb, dead after attn)

    cvt_all<<<6914, 256, 0, stream>>>(qkv_w, proj_w, fc1_w, fc2_w,
                                      wqkv, wproj, wfc1, wfc2,
                                      mask, posb, cntb);

    ln_kernel<<<NTOK, 256, 0, stream>>>(x, ln1_g, ln1_b, hbuf);
    mgemm<128, 128, 0><<<dim3(QKVC / 128, NTOK / 128), 256, 0, stream>>>(
        hbuf, wqkv, qkvb, nullptr, QKVC, DIM, nullptr, nullptr);
    repack_kv<<<dim3(SEQ / 64, BATCH * HEADS), 256, 0, stream>>>(qkvb, posb, khb, vthb);
    attn_mfma<<<dim3(SEQ / 64, BATCH * HEADS), 256, 0, stream>>>(
        qkvb, khb, vthb, cntb, ybuf);
    mgemm<128, 64, 1><<<dim3(DIM / 64, NTOK / 128), 256, 0, stream>>>(
        ybuf, wproj, x1, nullptr, DIM, DIM, proj_b, x);
    ln_kernel<<<NTOK, 256, 0, stream>>>(x1, ln2_g, ln2_b, hbuf);
    mgemm<128, 128, 2><<<dim3(HIDDEN / 128, NTOK / 128), 256, 0, stream>>>(
        hbuf, wfc1, a1, nullptr, HIDDEN, DIM, fc1_b, nullptr);
    // FC2 split-K=2: z=0 -> pp, z=1 -> out (raw partials), then merge
    mgemm<128, 64, 3><<<dim3(DIM / 64, NTOK / 128, 2), 256, 0, stream>>>(
        a1, wfc2, pp, out, DIM, HIDDEN / 2, nullptr, nullptr);
    merge_kernel<<<NTOK * DIM / 1024, 256, 0, stream>>>(out, pp, fc2_b, x1);
}

// Round 8
// 264.712 us; speedup vs baseline: 1.6238x; 1.1007x over previous
//
#include <hip/hip_runtime.h>
#include <math.h>
#include <float.h>

#define DIM 768
#define HEADS 12
#define HD 64
#define HIDDEN 3072
#define SEQ 2048
#define BATCH 2
#define NTOK (BATCH * SEQ)   // 4096
#define QKVC (3 * DIM)       // 2304
#define LN_EPS 1e-5f
#define SC2 0.1803368801111f  // 0.125 * log2(e)

typedef unsigned short u16;
typedef __attribute__((ext_vector_type(8))) __bf16 bf16x8;
typedef __attribute__((ext_vector_type(8))) unsigned short u16x8;
typedef __attribute__((ext_vector_type(4))) float f32x4;

__device__ __forceinline__ u16 f2bf(float f) {
    unsigned int u = __builtin_bit_cast(unsigned int, f);
    u += 0x7fffu + ((u >> 16) & 1u);
    return (u16)(u >> 16);
}

__device__ __forceinline__ f32x4 mfma16(u16x8 a, u16x8 b, f32x4 c) {
    return __builtin_amdgcn_mfma_f32_16x16x32_bf16(
        __builtin_bit_cast(bf16x8, a), __builtin_bit_cast(bf16x8, b), c, 0, 0, 0);
}

__device__ __forceinline__ void gl2lds16(const void* g, void* l) {
    __builtin_amdgcn_global_load_lds(
        (const __attribute__((address_space(1))) void*)g,
        (__attribute__((address_space(3))) void*)l, 16, 0, 0);
}

__device__ __forceinline__ float gelu_f(float v) {
    return 0.5f * v * (1.0f + erff(v * 0.70710678118654752f));
}

// ------- fused: fp32->bf16 weight convert (blocks 0..6911) + mask scan (6912..6913)
__global__ __launch_bounds__(256) void cvt_all(const float* __restrict__ qkvw,
                                               const float* __restrict__ projw,
                                               const float* __restrict__ fc1w,
                                               const float* __restrict__ fc2w,
                                               u16* __restrict__ o_qkv,
                                               u16* __restrict__ o_proj,
                                               u16* __restrict__ o_fc1,
                                               u16* __restrict__ o_fc2,
                                               const int* __restrict__ mask,
                                               int* __restrict__ pos,
                                               int* __restrict__ cnt) {
    if (blockIdx.x >= 6912) {   // ---- mask scan, one block per batch ----
        int b = blockIdx.x - 6912, t = threadIdx.x;
        const int* m = mask + b * SEQ;
        int v[8], s = 0;
#pragma unroll
        for (int j = 0; j < 8; ++j) { v[j] = (m[t * 8 + j] == 1) ? 0 : 1; s += v[j]; }
        __shared__ int red[256];
        red[t] = s;
        __syncthreads();
        for (int off = 1; off < 256; off <<= 1) {
            int x = (t >= off) ? red[t - off] : 0;
            __syncthreads();
            red[t] += x;
            __syncthreads();
        }
        int base = red[t] - s;
#pragma unroll
        for (int j = 0; j < 8; ++j) {
            pos[b * SEQ + t * 8 + j] = v[j] ? base : -1;
            base += v[j];
        }
        if (t == 255) cnt[b] = red[255];
        return;
    }
    long i = (long)(blockIdx.x * 256 + threadIdx.x) * 4;
    const float* s; u16* d; long off;
    if (i < 1769472)      { s = qkvw;  d = o_qkv;  off = i; }
    else if (i < 2359296) { s = projw; d = o_proj; off = i - 1769472; }
    else if (i < 4718592) { s = fc1w;  d = o_fc1;  off = i - 2359296; }
    else                  { s = fc2w;  d = o_fc2;  off = i - 4718592; }
    float4 v = *(const float4*)(s + off);
    ushort4 o;
    o.x = f2bf(v.x); o.y = f2bf(v.y); o.z = f2bf(v.z); o.w = f2bf(v.w);
    *(ushort4*)(d + off) = o;
}

// ---------------- LayerNorm: fp32 in, bf16 out ----------------
__global__ __launch_bounds__(256) void ln_kernel(const float* __restrict__ x,
                                                 const float* __restrict__ g,
                                                 const float* __restrict__ bta,
                                                 u16* __restrict__ out) {
    int row = blockIdx.x;
    int t = threadIdx.x;
    const float* xr = x + (size_t)row * DIM;
    float v0 = xr[t], v1 = xr[t + 256], v2 = xr[t + 512];
    __shared__ float red[256];
    red[t] = v0 + v1 + v2;
    __syncthreads();
    for (int off = 128; off > 0; off >>= 1) {
        if (t < off) red[t] += red[t + off];
        __syncthreads();
    }
    float mean = red[0] * (1.0f / DIM);
    __syncthreads();
    float d0 = v0 - mean, d1 = v1 - mean, d2 = v2 - mean;
    red[t] = d0 * d0 + d1 * d1 + d2 * d2;
    __syncthreads();
    for (int off = 128; off > 0; off >>= 1) {
        if (t < off) red[t] += red[t + off];
        __syncthreads();
    }
    float rstd = rsqrtf(red[0] * (1.0f / DIM) + LN_EPS);
    u16* orow = out + (size_t)row * DIM;
    orow[t]       = f2bf(d0 * rstd * g[t]       + bta[t]);
    orow[t + 256] = f2bf(d1 * rstd * g[t + 256] + bta[t + 256]);
    orow[t + 512] = f2bf(d2 * rstd * g[t + 512] + bta[t + 512]);
}

// ---------------- repack+compact: K -> [bh][cpos][d], V -> [bh][d][cpos] -------
__global__ __launch_bounds__(256) void repack_kv(const u16* __restrict__ qkv,
                                                 const int* __restrict__ pos,
                                                 u16* __restrict__ kh,
                                                 u16* __restrict__ vth) {
    int s = blockIdx.x;          // 64-token tile
    int bh = blockIdx.y;
    int b = bh / HEADS, h = bh % HEADS;
    int t = threadIdx.x;
    __shared__ u16 Vl[64 * 72];
    __shared__ int lpos[64];
    const u16* base = qkv + ((size_t)(b * SEQ + s * 64)) * QKVC + h * HD;
    if (t < 64) lpos[t] = pos[b * SEQ + s * 64 + t];
    {   // V: transpose via LDS (packed b32 writes), all 64 keys
        int vkey = (t & 31) * 2, vd0 = (t >> 5) * 8;
        const u16* g0 = base + 2 * DIM + (size_t)vkey * QKVC + vd0;
        u16x8 a = *(const u16x8*)g0;
        u16x8 c = *(const u16x8*)(g0 + QKVC);
#pragma unroll
        for (int j = 0; j < 8; ++j) {
            unsigned int pk = (unsigned int)a[j] | ((unsigned int)c[j] << 16);
            *(unsigned int*)(Vl + (vd0 + j) * 72 + vkey) = pk;
        }
    }
    __syncthreads();
    {   // K: compacted row scatter
        int r = t >> 2, d0 = (t & 3) * 16;
        int p = lpos[r];
        if (p >= 0) {
            const u16* g = base + DIM + (size_t)r * QKVC + d0;
            u16* o = kh + (size_t)bh * (SEQ * HD) + (size_t)p * HD + d0;
            *(uint4*)o = *(const uint4*)g;
            *(uint4*)(o + 8) = *(const uint4*)(g + 8);
        }
    }
    {   // V^T: write only unmasked columns
        int d = t >> 2, m0 = (t & 3) * 16;
        u16* orow = vth + (size_t)bh * (HD * SEQ) + (size_t)d * SEQ;
#pragma unroll
        for (int j = 0; j < 16; ++j) {
            int p = lpos[m0 + j];
            if (p >= 0) orow[p] = Vl[d * 72 + m0 + j];
        }
    }
}

// ---------------- MFMA GEMM, BK=64, XOR-swizzled LDS ----------------
// C = A (MxK) * Bw^T (Bw NxK), bf16 in.
// LDS layout: row stride 64 u16 (128 B); chunk c (16 B) of row r at slot c^(r&7).
// EPI 0: bf16 plain; 1: fp32 +bias+resid; 2: bf16 gelu(v+bias);
// EPI 4: split-K pair: z=0 raw fp32 -> Cout, z=1 (+bias+resid) -> Cout2,
//        with A-panel XCD swizzle (same by -> same XCD L2).
template <int BM, int BN, int EPI>
__global__ __launch_bounds__(256) void mgemm(const u16* __restrict__ A,
                                             const u16* __restrict__ Bw,
                                             void* __restrict__ Cout,
                                             void* __restrict__ Cout2,
                                             int N, int klen,
                                             const float* __restrict__ bias,
                                             const float* __restrict__ resid) {
    constexpr int WM = BM / 2, WN = BN / 2, NI = WM / 16, NJ = WN / 16;
    constexpr int ACALLS = (BM * 128) / 4096;   // 1KB per wave-call
    constexpr int BCALLS = (BN * 128) / 4096;
    __shared__ u16 As[BM * 64];
    __shared__ u16 Bs[BN * 64];
    int t = threadIdx.x;
    int w = t >> 6, lane = t & 63;
    int quad = lane >> 4, m16 = lane & 15;
    int bx = blockIdx.x, by = blockIdx.y;
    if (EPI == 4) {   // FC2: A-panel XCD grouping (gridDim.y=32, /8 ok)
        int gx = gridDim.x;
        int flat = by * gx + bx;
        bx = (flat >> 3) % gx;
        by = (flat & 7) + 8 * ((flat >> 3) / gx);
    }
    int K = klen * gridDim.z;                  // full K (row stride of A/B)
    int kbeg = blockIdx.z * klen;
    int row0 = by * BM, col0 = bx * BN;
    int lrow = lane >> 3;              // 0..7: row within a call-group
    int lk = (lane & 7) ^ lrow;        // swizzled global k-chunk for this lane

    f32x4 acc[NI][NJ] = {};

    for (int k0 = kbeg; k0 < kbeg + klen; k0 += 64) {
        __syncthreads();
#pragma unroll
        for (int c = 0; c < ACALLS; ++c) {
            int r = (w * ACALLS + c) * 8 + lrow;
            const u16* g = A + (size_t)(row0 + r) * K + k0 + lk * 8;
            gl2lds16(g, As + (w * ACALLS + c) * 512);
        }
#pragma unroll
        for (int c = 0; c < BCALLS; ++c) {
            int r = (w * BCALLS + c) * 8 + lrow;
            const u16* g = Bw + (size_t)(col0 + r) * K + k0 + lk * 8;
            gl2lds16(g, Bs + (w * BCALLS + c) * 512);
        }
        __syncthreads();
#pragma unroll
        for (int ks = 0; ks < 2; ++ks) {
            u16x8 af[NI], bfj[NJ];
#pragma unroll
            for (int i = 0; i < NI; ++i) {
                int rowL = (w >> 1) * WM + 16 * i + m16;
                af[i] = *(const u16x8*)(As + rowL * 64 +
                                        (((ks * 4 + quad) ^ (rowL & 7)) * 8));
            }
#pragma unroll
            for (int j = 0; j < NJ; ++j) {
                int rowL = (w & 1) * WN + 16 * j + m16;
                bfj[j] = *(const u16x8*)(Bs + rowL * 64 +
                                         (((ks * 4 + quad) ^ (rowL & 7)) * 8));
            }
#pragma unroll
            for (int i = 0; i < NI; ++i)
#pragma unroll
                for (int j = 0; j < NJ; ++j)
                    acc[i][j] = mfma16(af[i], bfj[j], acc[i][j]);
        }
    }

    int wr0 = row0 + (w >> 1) * WM, wc0 = col0 + (w & 1) * WN;
#pragma unroll
    for (int i = 0; i < NI; ++i)
#pragma unroll
        for (int j = 0; j < NJ; ++j) {
            int ccol = wc0 + 16 * j + m16;
#pragma unroll
            for (int r = 0; r < 4; ++r) {
                int crow = wr0 + 16 * i + quad * 4 + r;
                float v = acc[i][j][r];
                if (EPI == 0) {
                    ((u16*)Cout)[(size_t)crow * N + ccol] = f2bf(v);
                } else if (EPI == 1) {
                    v += bias[ccol] + resid[(size_t)crow * N + ccol];
                    ((float*)Cout)[(size_t)crow * N + ccol] = v;
                } else if (EPI == 2) {
                    v = gelu_f(v + bias[ccol]);
                    ((u16*)Cout)[(size_t)crow * N + ccol] = f2bf(v);
                } else {
                    if (blockIdx.z == 0) {
                        ((float*)Cout)[(size_t)crow * N + ccol] = v;
                    } else {
                        v += bias[ccol] + resid[(size_t)crow * N + ccol];
                        ((float*)Cout2)[(size_t)crow * N + ccol] = v;
                    }
                }
            }
        }
}

// ---------------- split-K merge: out += part ----------------
__global__ __launch_bounds__(256) void merge_kernel(float* __restrict__ out,
                                                    const float* __restrict__ part) {
    int i = (blockIdx.x * 256 + threadIdx.x) * 4;
    float4 o = *(const float4*)(out + i);
    float4 p = *(const float4*)(part + i);
    o.x += p.x; o.y += p.y; o.z += p.z; o.w += p.w;
    *(float4*)(out + i) = o;
}

// ---------------- Flash attention, bf16 MFMA, compacted 128-key tiles -----------
// Fixed-base softmax (M0=0): base-2 scores provably < 2^127, so no running max,
// no rescale; per-lane sums deferred to one end-of-kernel tree.
__global__ __launch_bounds__(256, 3) void attn_mfma(const u16* __restrict__ qkv,
                                                    const u16* __restrict__ kh,
                                                    const u16* __restrict__ vth,
                                                    const int* __restrict__ cnt,
                                                    u16* __restrict__ y) {
    int gx = gridDim.x;
    int flat = blockIdx.y * gx + blockIdx.x;
    int qt = (flat >> 3) % gx;
    int bh = (flat & 7) + 8 * ((flat >> 3) / gx);
    int b = bh / HEADS, h = bh % HEADS;
    int t = threadIdx.x, w = t >> 6, lane = t & 63;
    int quad = lane >> 4, m16 = lane & 15;
    __shared__ u16 Ks[128 * 64];       // 16 KB
    __shared__ u16 Vt[64 * 128];       // 16 KB
    __shared__ u16 Pw[4][16 * 136];    // 17 KB, per-wave P round-trip
    const u16* kbase = kh + (size_t)bh * (SEQ * HD);
    const u16* vbase = vth + (size_t)bh * (SEQ * HD);

    int qrow = b * SEQ + qt * 64 + w * 16 + m16;
    const u16* qp = qkv + (size_t)qrow * QKVC + h * HD + quad * 8;
    u16x8 qf0 = *(const u16x8*)qp;
    u16x8 qf1 = *(const u16x8*)(qp + 32);

    int rloc = lane >> 3, kslot = lane & 7;   // K: 8 rows x 8 chunks per call
    int kchunk = kslot ^ rloc;
    int dloc = lane >> 4, vslot = lane & 15;  // V: 4 rows x 16 chunks per call

    float lsum[4] = {0.f, 0.f, 0.f, 0.f};
    f32x4 O[4] = {};

    int slo = quad ^ (m16 & 7);               // K read slots (hi = slo^4)

    int cntb = cnt[b];
    int ntile = (cntb + 127) >> 7;

    for (int kt = 0; kt < ntile; ++kt) {
        int k0 = kt << 7;
        __syncthreads();
#pragma unroll
        for (int c = 0; c < 4; ++c) {         // K tile: 16 KB via 16 DMA calls
            int rb = (w * 4 + c) * 8;
            const u16* g = kbase + (size_t)(k0 + rb + rloc) * HD + kchunk * 8;
            gl2lds16(g, Ks + (w * 4 + c) * 512);
        }
#pragma unroll
        for (int c = 0; c < 4; ++c) {         // V tile
            int d = (w * 4 + c) * 4 + dloc;
            int chunk = vslot ^ (d & 15);
            const u16* g = vbase + (size_t)d * SEQ + k0 + chunk * 8;
            gl2lds16(g, Vt + (w * 4 + c) * 512);
        }
        float kb[8];
#pragma unroll
        for (int nb = 0; nb < 8; ++nb)
            kb[nb] = (k0 + m16 + 16 * nb < cntb) ? 0.0f : -1e30f;
        __syncthreads();

        // P = exp2(S*SC2 + kb), accumulated per-lane (no max, no rescale)
#pragma unroll
        for (int nb = 0; nb < 8; ++nb) {
            const u16* krow = Ks + (m16 + 16 * nb) * 64;
            f32x4 s = {0.f, 0.f, 0.f, 0.f};
            s = mfma16(qf0, *(const u16x8*)(krow + slo * 8), s);
            s = mfma16(qf1, *(const u16x8*)(krow + (slo ^ 4) * 8), s);
#pragma unroll
            for (int r = 0; r < 4; ++r) {
                float p = __builtin_amdgcn_exp2f(s[r] * SC2 + kb[nb]);
                lsum[r] += p;
                Pw[w][(quad * 4 + r) * 136 + m16 + 16 * nb] = f2bf(p);
            }
        }
        u16x8 pf[4];
#pragma unroll
        for (int ks = 0; ks < 4; ++ks)
            pf[ks] = *(const u16x8*)(Pw[w] + m16 * 136 + ks * 32 + quad * 8);
#pragma unroll
        for (int nbd = 0; nbd < 4; ++nbd) {
            const u16* vrow = Vt + (nbd * 16 + m16) * 128;
#pragma unroll
            for (int ks = 0; ks < 4; ++ks) {
                int sl = (quad + 4 * ks) ^ m16;
                O[nbd] = mfma16(pf[ks], *(const u16x8*)(vrow + sl * 8), O[nbd]);
            }
        }
    }
    // one sum-tree at the end (16-lane groups share rows)
#pragma unroll
    for (int off = 1; off < 16; off <<= 1)
#pragma unroll
        for (int r = 0; r < 4; ++r)
            lsum[r] += __shfl_xor(lsum[r], off);
#pragma unroll
    for (int r = 0; r < 4; ++r) {
        float inv = 1.0f / lsum[r];
        int tok = b * SEQ + qt * 64 + w * 16 + quad * 4 + r;
        u16* yr = y + (size_t)tok * DIM + h * HD + m16;
#pragma unroll
        for (int nbd = 0; nbd < 4; ++nbd) yr[16 * nbd] = f2bf(O[nbd][r] * inv);
    }
}

extern "C" void kernel_launch(void* const* d_in, const int* in_sizes, int n_in,
                              void* d_out, int out_size, void* d_ws, size_t ws_size,
                              hipStream_t stream) {
    const float* x      = (const float*)d_in[0];
    const int*   mask   = (const int*)d_in[1];
    const float* ln1_g  = (const float*)d_in[2];
    const float* ln1_b  = (const float*)d_in[3];
    const float* qkv_w  = (const float*)d_in[4];
    const float* proj_w = (const float*)d_in[5];
    const float* proj_b = (const float*)d_in[6];
    const float* ln2_g  = (const float*)d_in[7];
    const float* ln2_b  = (const float*)d_in[8];
    const float* fc1_w  = (const float*)d_in[9];
    const float* fc1_b  = (const float*)d_in[10];
    const float* fc2_w  = (const float*)d_in[11];
    const float* fc2_b  = (const float*)d_in[12];
    float* out = (float*)d_out;

    // workspace layout (bytes)
    char* W = (char*)d_ws;
    u16*   wqkv  = (u16*)(W + 0);           // 2304x768   bf16
    u16*   wproj = (u16*)(W + 3538944);     // 768x768
    u16*   wfc1  = (u16*)(W + 4718592);     // 3072x768
    u16*   wfc2  = (u16*)(W + 9437184);     // 768x3072
    u16*   hbuf  = (u16*)(W + 14155776);    // 4096x768   bf16 (ln out, reused)
    float* x1    = (float*)(W + 20447232);  // 4096x768   fp32
    // scan outputs alias x1's head: dead before proj GEMM writes x1
    int*   posb  = (int*)(W + 20463616);    // 4096 int
    int*   cntb  = (int*)(W + 20480000);    // 2 int
    u16*   qkvb  = (u16*)(W + 33030144);    // 4096x2304  bf16
    u16*   ybuf  = (u16*)(W + 51904512);    // 4096x768   bf16
    u16*   a1    = (u16*)(W + 33030144);    // 4096x3072  bf16, aliases qkvb+ybuf (dead)
    u16*   khb   = (u16*)(W + 58212352);    // 24x2048x64 bf16 (compacted keys)
    u16*   vthb  = (u16*)(W + 64503808);    // 24x64x2048 bf16 (ends 70.8MB)
    float* pp    = (float*)(W + 58212352);  // 4096x768 fp32 split-K partial
                                            // (reuses khb+vthb, dead after attn)

    cvt_all<<<6914, 256, 0, stream>>>(qkv_w, proj_w, fc1_w, fc2_w,
                                      wqkv, wproj, wfc1, wfc2,
                                      mask, posb, cntb);

    ln_kernel<<<NTOK, 256, 0, stream>>>(x, ln1_g, ln1_b, hbuf);
    mgemm<128, 128, 0><<<dim3(QKVC / 128, NTOK / 128), 256, 0, stream>>>(
        hbuf, wqkv, qkvb, nullptr, QKVC, DIM, nullptr, nullptr);
    repack_kv<<<dim3(SEQ / 64, BATCH * HEADS), 256, 0, stream>>>(qkvb, posb, khb, vthb);
    attn_mfma<<<dim3(SEQ / 64, BATCH * HEADS), 256, 0, stream>>>(
        qkvb, khb, vthb, cntb, ybuf);
    mgemm<128, 64, 1><<<dim3(DIM / 64, NTOK / 128), 256, 0, stream>>>(
        ybuf, wproj, x1, nullptr, DIM, DIM, proj_b, x);
    ln_kernel<<<NTOK, 256, 0, stream>>>(x1, ln2_g, ln2_b, hbuf);
    mgemm<128, 128, 2><<<dim3(HIDDEN / 128, NTOK / 128), 256, 0, stream>>>(
        hbuf, wfc1, a1, nullptr, HIDDEN, DIM, fc1_b, nullptr);
    // FC2 split-K=2: z=0 -> pp (raw), z=1 -> out (+bias+resid), then out += pp
    mgemm<128, 64, 4><<<dim3(DIM / 64, NTOK / 128, 2), 256, 0, stream>>>(
        a1, wfc2, pp, out, DIM, HIDDEN / 2, fc2_b, x1);
    merge_kernel<<<NTOK * DIM / 1024, 256, 0, stream>>>(out, pp);
}

// Round 9
// 263.441 us; speedup vs baseline: 1.6316x; 1.0048x over previous
//
#include <hip/hip_runtime.h>
#include <math.h>
#include <float.h>

#define DIM 768
#define HEADS 12
#define HD 64
#define HIDDEN 3072
#define SEQ 2048
#define BATCH 2
#define NTOK (BATCH * SEQ)   // 4096
#define QKVC (3 * DIM)       // 2304
#define LN_EPS 1e-5f
#define SC2 0.1803368801111f  // 0.125 * log2(e)

typedef unsigned short u16;
typedef __attribute__((ext_vector_type(8))) __bf16 bf16x8;
typedef __attribute__((ext_vector_type(8))) unsigned short u16x8;
typedef __attribute__((ext_vector_type(4))) float f32x4;

__device__ __forceinline__ u16 f2bf(float f) {
    unsigned int u = __builtin_bit_cast(unsigned int, f);
    u += 0x7fffu + ((u >> 16) & 1u);
    return (u16)(u >> 16);
}

__device__ __forceinline__ f32x4 mfma16(u16x8 a, u16x8 b, f32x4 c) {
    return __builtin_amdgcn_mfma_f32_16x16x32_bf16(
        __builtin_bit_cast(bf16x8, a), __builtin_bit_cast(bf16x8, b), c, 0, 0, 0);
}

__device__ __forceinline__ void gl2lds16(const void* g, void* l) {
    __builtin_amdgcn_global_load_lds(
        (const __attribute__((address_space(1))) void*)g,
        (__attribute__((address_space(3))) void*)l, 16, 0, 0);
}

__device__ __forceinline__ float gelu_f(float v) {
    return 0.5f * v * (1.0f + erff(v * 0.70710678118654752f));
}

// -------- wave-per-row LayerNorm body: fp32 in, bf16 out, shuffle-only --------
__device__ __forceinline__ void ln_row(const float* __restrict__ xr,
                                       const float* __restrict__ g,
                                       const float* __restrict__ bta,
                                       u16* __restrict__ orow, int lane) {
    float4 v0 = *(const float4*)(xr + lane * 4);
    float4 v1 = *(const float4*)(xr + 256 + lane * 4);
    float4 v2 = *(const float4*)(xr + 512 + lane * 4);
    float s = v0.x + v0.y + v0.z + v0.w + v1.x + v1.y + v1.z + v1.w +
              v2.x + v2.y + v2.z + v2.w;
#pragma unroll
    for (int off = 1; off < 64; off <<= 1) s += __shfl_xor(s, off);
    float mean = s * (1.0f / DIM);
    float d[12] = {v0.x - mean, v0.y - mean, v0.z - mean, v0.w - mean,
                   v1.x - mean, v1.y - mean, v1.z - mean, v1.w - mean,
                   v2.x - mean, v2.y - mean, v2.z - mean, v2.w - mean};
    float q = 0.f;
#pragma unroll
    for (int i = 0; i < 12; ++i) q += d[i] * d[i];
#pragma unroll
    for (int off = 1; off < 64; off <<= 1) q += __shfl_xor(q, off);
    float rstd = rsqrtf(q * (1.0f / DIM) + LN_EPS);
#pragma unroll
    for (int p = 0; p < 3; ++p) {
        int col = p * 256 + lane * 4;
        float4 gg = *(const float4*)(g + col);
        float4 bb = *(const float4*)(bta + col);
        ushort4 o;
        o.x = f2bf(d[p * 4 + 0] * rstd * gg.x + bb.x);
        o.y = f2bf(d[p * 4 + 1] * rstd * gg.y + bb.y);
        o.z = f2bf(d[p * 4 + 2] * rstd * gg.z + bb.z);
        o.w = f2bf(d[p * 4 + 3] * rstd * gg.w + bb.w);
        *(ushort4*)(orow + col) = o;
    }
}

// ------- fused: weight convert (0..6911) + mask scan (6912..6913) + LN1 (6914..)
__global__ __launch_bounds__(256) void cvt_all(const float* __restrict__ qkvw,
                                               const float* __restrict__ projw,
                                               const float* __restrict__ fc1w,
                                               const float* __restrict__ fc2w,
                                               u16* __restrict__ o_qkv,
                                               u16* __restrict__ o_proj,
                                               u16* __restrict__ o_fc1,
                                               u16* __restrict__ o_fc2,
                                               const int* __restrict__ mask,
                                               int* __restrict__ pos,
                                               int* __restrict__ cnt,
                                               const float* __restrict__ x,
                                               const float* __restrict__ ln1_g,
                                               const float* __restrict__ ln1_b,
                                               u16* __restrict__ hbuf) {
    if (blockIdx.x >= 6914) {   // ---- LN1: 4 rows per block, wave per row ----
        int w = threadIdx.x >> 6, lane = threadIdx.x & 63;
        int row = (blockIdx.x - 6914) * 4 + w;
        ln_row(x + (size_t)row * DIM, ln1_g, ln1_b, hbuf + (size_t)row * DIM, lane);
        return;
    }
    if (blockIdx.x >= 6912) {   // ---- mask scan, one block per batch ----
        int b = blockIdx.x - 6912, t = threadIdx.x;
        const int* m = mask + b * SEQ;
        int v[8], s = 0;
#pragma unroll
        for (int j = 0; j < 8; ++j) { v[j] = (m[t * 8 + j] == 1) ? 0 : 1; s += v[j]; }
        __shared__ int red[256];
        red[t] = s;
        __syncthreads();
        for (int off = 1; off < 256; off <<= 1) {
            int xv = (t >= off) ? red[t - off] : 0;
            __syncthreads();
            red[t] += xv;
            __syncthreads();
        }
        int base = red[t] - s;
#pragma unroll
        for (int j = 0; j < 8; ++j) {
            pos[b * SEQ + t * 8 + j] = v[j] ? base : -1;
            base += v[j];
        }
        if (t == 255) cnt[b] = red[255];
        return;
    }
    long i = (long)(blockIdx.x * 256 + threadIdx.x) * 4;
    const float* s; u16* d; long off;
    if (i < 1769472)      { s = qkvw;  d = o_qkv;  off = i; }
    else if (i < 2359296) { s = projw; d = o_proj; off = i - 1769472; }
    else if (i < 4718592) { s = fc1w;  d = o_fc1;  off = i - 2359296; }
    else                  { s = fc2w;  d = o_fc2;  off = i - 4718592; }
    float4 v = *(const float4*)(s + off);
    ushort4 o;
    o.x = f2bf(v.x); o.y = f2bf(v.y); o.z = f2bf(v.z); o.w = f2bf(v.w);
    *(ushort4*)(d + off) = o;
}

// ---------------- LN2: wave per row ----------------
__global__ __launch_bounds__(256) void ln2_kernel(const float* __restrict__ x,
                                                  const float* __restrict__ g,
                                                  const float* __restrict__ bta,
                                                  u16* __restrict__ out) {
    int w = threadIdx.x >> 6, lane = threadIdx.x & 63;
    int row = blockIdx.x * 4 + w;
    ln_row(x + (size_t)row * DIM, g, bta, out + (size_t)row * DIM, lane);
}

// ---------------- repack+compact: K -> [bh][cpos][d], V -> [bh][d][cpos] -------
__global__ __launch_bounds__(256) void repack_kv(const u16* __restrict__ qkv,
                                                 const int* __restrict__ pos,
                                                 u16* __restrict__ kh,
                                                 u16* __restrict__ vth) {
    int s = blockIdx.x;          // 64-token tile
    int bh = blockIdx.y;
    int b = bh / HEADS, h = bh % HEADS;
    int t = threadIdx.x;
    __shared__ u16 Vl[64 * 72];
    __shared__ int lpos[64];
    const u16* base = qkv + ((size_t)(b * SEQ + s * 64)) * QKVC + h * HD;
    if (t < 64) lpos[t] = pos[b * SEQ + s * 64 + t];
    {   // V: transpose via LDS (packed b32 writes), all 64 keys
        int vkey = (t & 31) * 2, vd0 = (t >> 5) * 8;
        const u16* g0 = base + 2 * DIM + (size_t)vkey * QKVC + vd0;
        u16x8 a = *(const u16x8*)g0;
        u16x8 c = *(const u16x8*)(g0 + QKVC);
#pragma unroll
        for (int j = 0; j < 8; ++j) {
            unsigned int pk = (unsigned int)a[j] | ((unsigned int)c[j] << 16);
            *(unsigned int*)(Vl + (vd0 + j) * 72 + vkey) = pk;
        }
    }
    __syncthreads();
    {   // K: compacted row scatter
        int r = t >> 2, d0 = (t & 3) * 16;
        int p = lpos[r];
        if (p >= 0) {
            const u16* g = base + DIM + (size_t)r * QKVC + d0;
            u16* o = kh + (size_t)bh * (SEQ * HD) + (size_t)p * HD + d0;
            *(uint4*)o = *(const uint4*)g;
            *(uint4*)(o + 8) = *(const uint4*)(g + 8);
        }
    }
    {   // V^T: write only unmasked columns
        int d = t >> 2, m0 = (t & 3) * 16;
        u16* orow = vth + (size_t)bh * (HD * SEQ) + (size_t)d * SEQ;
#pragma unroll
        for (int j = 0; j < 16; ++j) {
            int p = lpos[m0 + j];
            if (p >= 0) orow[p] = Vl[d * 72 + m0 + j];
        }
    }
}

// ---------------- MFMA GEMM, templated BK, XOR-swizzled LDS ----------------
// C = A (MxK) * Bw^T (Bw NxK), bf16 in.
// LDS: row stride BK u16; 16B chunk c of row r at slot c^(r&(BK/8-1)).
// EPI 0: bf16 plain; 1: fp32 +bias+resid; 2: bf16 gelu(v+bias);
// EPI 4: split-K pair: z=0 raw fp32 -> Cout, z=last (+bias+resid) -> Cout2,
//        with A-panel XCD swizzle (same by -> same XCD L2).
template <int BM, int BN, int BK, int EPI>
__global__ __launch_bounds__(256) void mgemm(const u16* __restrict__ A,
                                             const u16* __restrict__ Bw,
                                             void* __restrict__ Cout,
                                             void* __restrict__ Cout2,
                                             int N, int klen,
                                             const float* __restrict__ bias,
                                             const float* __restrict__ resid) {
    constexpr int WM = BM / 2, WN = BN / 2, NI = WM / 16, NJ = WN / 16;
    constexpr int CH = BK / 8;             // 16B chunks per row
    constexpr int RPC = 512 / BK;          // rows per 1KB DMA call
    constexpr int ACALLS = (BM * BK) / 2048;   // calls per wave
    constexpr int BCALLS = (BN * BK) / 2048;
    __shared__ u16 As[BM * BK];
    __shared__ u16 Bs[BN * BK];
    int t = threadIdx.x;
    int w = t >> 6, lane = t & 63;
    int quad = lane >> 4, m16 = lane & 15;
    int bx = blockIdx.x, by = blockIdx.y;
    if (EPI == 4) {   // FC2: A-panel XCD grouping (gridDim.y=32, /8 ok)
        int gx = gridDim.x;
        int flat = by * gx + bx;
        bx = (flat >> 3) % gx;
        by = (flat & 7) + 8 * ((flat >> 3) / gx);
    }
    int K = klen * gridDim.z;                  // full K (row stride of A/B)
    int kbeg = blockIdx.z * klen;
    int row0 = by * BM, col0 = bx * BN;
    int rloc = lane / CH;              // row within a call
    int cslot = lane % CH;             // LDS slot this lane fills

    f32x4 acc[NI][NJ] = {};

    for (int k0 = kbeg; k0 < kbeg + klen; k0 += BK) {
        __syncthreads();
#pragma unroll
        for (int c = 0; c < ACALLS; ++c) {
            int callrow = (w * ACALLS + c) * RPC;
            int r = callrow + rloc;
            int chunk = cslot ^ (r & (CH - 1));
            const u16* g = A + (size_t)(row0 + r) * K + k0 + chunk * 8;
            gl2lds16(g, As + (w * ACALLS + c) * 512);
        }
#pragma unroll
        for (int c = 0; c < BCALLS; ++c) {
            int callrow = (w * BCALLS + c) * RPC;
            int r = callrow + rloc;
            int chunk = cslot ^ (r & (CH - 1));
            const u16* g = Bw + (size_t)(col0 + r) * K + k0 + chunk * 8;
            gl2lds16(g, Bs + (w * BCALLS + c) * 512);
        }
        __syncthreads();
#pragma unroll
        for (int ks = 0; ks < BK / 32; ++ks) {
            u16x8 af[NI], bfj[NJ];
#pragma unroll
            for (int i = 0; i < NI; ++i) {
                int rowL = (w >> 1) * WM + 16 * i + m16;
                af[i] = *(const u16x8*)(As + rowL * BK +
                                        (((ks * 4 + quad) ^ (rowL & (CH - 1))) * 8));
            }
#pragma unroll
            for (int j = 0; j < NJ; ++j) {
                int rowL = (w & 1) * WN + 16 * j + m16;
                bfj[j] = *(const u16x8*)(Bs + rowL * BK +
                                         (((ks * 4 + quad) ^ (rowL & (CH - 1))) * 8));
            }
#pragma unroll
            for (int i = 0; i < NI; ++i)
#pragma unroll
                for (int j = 0; j < NJ; ++j)
                    acc[i][j] = mfma16(af[i], bfj[j], acc[i][j]);
        }
    }

    int wr0 = row0 + (w >> 1) * WM, wc0 = col0 + (w & 1) * WN;
#pragma unroll
    for (int i = 0; i < NI; ++i)
#pragma unroll
        for (int j = 0; j < NJ; ++j) {
            int ccol = wc0 + 16 * j + m16;
#pragma unroll
            for (int r = 0; r < 4; ++r) {
                int crow = wr0 + 16 * i + quad * 4 + r;
                float v = acc[i][j][r];
                if (EPI == 0) {
                    ((u16*)Cout)[(size_t)crow * N + ccol] = f2bf(v);
                } else if (EPI == 1) {
                    v += bias[ccol] + resid[(size_t)crow * N + ccol];
                    ((float*)Cout)[(size_t)crow * N + ccol] = v;
                } else if (EPI == 2) {
                    v = gelu_f(v + bias[ccol]);
                    ((u16*)Cout)[(size_t)crow * N + ccol] = f2bf(v);
                } else {
                    if (blockIdx.z == 0) {
                        ((float*)Cout)[(size_t)crow * N + ccol] = v;
                    } else {
                        v += bias[ccol] + resid[(size_t)crow * N + ccol];
                        ((float*)Cout2)[(size_t)crow * N + ccol] = v;
                    }
                }
            }
        }
}

// ---------------- split-K merge: out += part ----------------
__global__ __launch_bounds__(256) void merge_kernel(float* __restrict__ out,
                                                    const float* __restrict__ part) {
    int i = (blockIdx.x * 256 + threadIdx.x) * 4;
    float4 o = *(const float4*)(out + i);
    float4 p = *(const float4*)(part + i);
    o.x += p.x; o.y += p.y; o.z += p.z; o.w += p.w;
    *(float4*)(out + i) = o;
}

// ---------------- Flash attention, bf16 MFMA, compacted 128-key tiles -----------
// Fixed-base softmax (M0=0): base-2 scores provably < 2^127, so no running max,
// no rescale; per-lane sums deferred to one end-of-kernel tree.
__global__ __launch_bounds__(256, 3) void attn_mfma(const u16* __restrict__ qkv,
                                                    const u16* __restrict__ kh,
                                                    const u16* __restrict__ vth,
                                                    const int* __restrict__ cnt,
                                                    u16* __restrict__ y) {
    int gx = gridDim.x;
    int flat = blockIdx.y * gx + blockIdx.x;
    int qt = (flat >> 3) % gx;
    int bh = (flat & 7) + 8 * ((flat >> 3) / gx);
    int b = bh / HEADS, h = bh % HEADS;
    int t = threadIdx.x, w = t >> 6, lane = t & 63;
    int quad = lane >> 4, m16 = lane & 15;
    __shared__ u16 Ks[128 * 64];       // 16 KB
    __shared__ u16 Vt[64 * 128];       // 16 KB
    __shared__ u16 Pw[4][16 * 136];    // 17 KB, per-wave P round-trip
    const u16* kbase = kh + (size_t)bh * (SEQ * HD);
    const u16* vbase = vth + (size_t)bh * (SEQ * HD);

    int qrow = b * SEQ + qt * 64 + w * 16 + m16;
    const u16* qp = qkv + (size_t)qrow * QKVC + h * HD + quad * 8;
    u16x8 qf0 = *(const u16x8*)qp;
    u16x8 qf1 = *(const u16x8*)(qp + 32);

    int rloc = lane >> 3, kslot = lane & 7;   // K: 8 rows x 8 chunks per call
    int kchunk = kslot ^ rloc;
    int dloc = lane >> 4, vslot = lane & 15;  // V: 4 rows x 16 chunks per call

    float lsum[4] = {0.f, 0.f, 0.f, 0.f};
    f32x4 O[4] = {};

    int slo = quad ^ (m16 & 7);               // K read slots (hi = slo^4)

    int cntb = cnt[b];
    int ntile = (cntb + 127) >> 7;

    for (int kt = 0; kt < ntile; ++kt) {
        int k0 = kt << 7;
        __syncthreads();
#pragma unroll
        for (int c = 0; c < 4; ++c) {         // K tile: 16 KB via 16 DMA calls
            int rb = (w * 4 + c) * 8;
            const u16* g = kbase + (size_t)(k0 + rb + rloc) * HD + kchunk * 8;
            gl2lds16(g, Ks + (w * 4 + c) * 512);
        }
#pragma unroll
        for (int c = 0; c < 4; ++c) {         // V tile
            int d = (w * 4 + c) * 4 + dloc;
            int chunk = vslot ^ (d & 15);
            const u16* g = vbase + (size_t)d * SEQ + k0 + chunk * 8;
            gl2lds16(g, Vt + (w * 4 + c) * 512);
        }
        float kb[8];
#pragma unroll
        for (int nb = 0; nb < 8; ++nb)
            kb[nb] = (k0 + m16 + 16 * nb < cntb) ? 0.0f : -1e30f;
        __syncthreads();

        // P = exp2(S*SC2 + kb), accumulated per-lane (no max, no rescale)
#pragma unroll
        for (int nb = 0; nb < 8; ++nb) {
            const u16* krow = Ks + (m16 + 16 * nb) * 64;
            f32x4 s = {0.f, 0.f, 0.f, 0.f};
            s = mfma16(qf0, *(const u16x8*)(krow + slo * 8), s);
            s = mfma16(qf1, *(const u16x8*)(krow + (slo ^ 4) * 8), s);
#pragma unroll
            for (int r = 0; r < 4; ++r) {
                float p = __builtin_amdgcn_exp2f(s[r] * SC2 + kb[nb]);
                lsum[r] += p;
                Pw[w][(quad * 4 + r) * 136 + m16 + 16 * nb] = f2bf(p);
            }
        }
        u16x8 pf[4];
#pragma unroll
        for (int ks = 0; ks < 4; ++ks)
            pf[ks] = *(const u16x8*)(Pw[w] + m16 * 136 + ks * 32 + quad * 8);
#pragma unroll
        for (int nbd = 0; nbd < 4; ++nbd) {
            const u16* vrow = Vt + (nbd * 16 + m16) * 128;
#pragma unroll
            for (int ks = 0; ks < 4; ++ks) {
                int sl = (quad + 4 * ks) ^ m16;
                O[nbd] = mfma16(pf[ks], *(const u16x8*)(vrow + sl * 8), O[nbd]);
            }
        }
    }
    // one sum-tree at the end (16-lane groups share rows)
#pragma unroll
    for (int off = 1; off < 16; off <<= 1)
#pragma unroll
        for (int r = 0; r < 4; ++r)
            lsum[r] += __shfl_xor(lsum[r], off);
#pragma unroll
    for (int r = 0; r < 4; ++r) {
        float inv = 1.0f / lsum[r];
        int tok = b * SEQ + qt * 64 + w * 16 + quad * 4 + r;
        u16* yr = y + (size_t)tok * DIM + h * HD + m16;
#pragma unroll
        for (int nbd = 0; nbd < 4; ++nbd) yr[16 * nbd] = f2bf(O[nbd][r] * inv);
    }
}

extern "C" void kernel_launch(void* const* d_in, const int* in_sizes, int n_in,
                              void* d_out, int out_size, void* d_ws, size_t ws_size,
                              hipStream_t stream) {
    const float* x      = (const float*)d_in[0];
    const int*   mask   = (const int*)d_in[1];
    const float* ln1_g  = (const float*)d_in[2];
    const float* ln1_b  = (const float*)d_in[3];
    const float* qkv_w  = (const float*)d_in[4];
    const float* proj_w = (const float*)d_in[5];
    const float* proj_b = (const float*)d_in[6];
    const float* ln2_g  = (const float*)d_in[7];
    const float* ln2_b  = (const float*)d_in[8];
    const float* fc1_w  = (const float*)d_in[9];
    const float* fc1_b  = (const float*)d_in[10];
    const float* fc2_w  = (const float*)d_in[11];
    const float* fc2_b  = (const float*)d_in[12];
    float* out = (float*)d_out;

    // workspace layout (bytes)
    char* W = (char*)d_ws;
    u16*   wqkv  = (u16*)(W + 0);           // 2304x768   bf16
    u16*   wproj = (u16*)(W + 3538944);     // 768x768
    u16*   wfc1  = (u16*)(W + 4718592);     // 3072x768
    u16*   wfc2  = (u16*)(W + 9437184);     // 768x3072
    u16*   hbuf  = (u16*)(W + 14155776);    // 4096x768   bf16 (ln out, reused)
    float* x1    = (float*)(W + 20447232);  // 4096x768   fp32
    // scan outputs alias x1's head: dead before proj GEMM writes x1
    int*   posb  = (int*)(W + 20463616);    // 4096 int
    int*   cntb  = (int*)(W + 20480000);    // 2 int
    u16*   qkvb  = (u16*)(W + 33030144);    // 4096x2304  bf16
    u16*   ybuf  = (u16*)(W + 51904512);    // 4096x768   bf16
    u16*   a1    = (u16*)(W + 33030144);    // 4096x3072  bf16, aliases qkvb+ybuf (dead)
    u16*   khb   = (u16*)(W + 58212352);    // 24x2048x64 bf16 (compacted keys)
    u16*   vthb  = (u16*)(W + 64503808);    // 24x64x2048 bf16 (ends 70.8MB)
    float* pp    = (float*)(W + 58212352);  // 4096x768 fp32 split-K partial
                                            // (reuses khb+vthb, dead after attn)

    cvt_all<<<7938, 256, 0, stream>>>(qkv_w, proj_w, fc1_w, fc2_w,
                                      wqkv, wproj, wfc1, wfc2,
                                      mask, posb, cntb,
                                      x, ln1_g, ln1_b, hbuf);

    mgemm<128, 128, 64, 0><<<dim3(QKVC / 128, NTOK / 128), 256, 0, stream>>>(
        hbuf, wqkv, qkvb, nullptr, QKVC, DIM, nullptr, nullptr);
    repack_kv<<<dim3(SEQ / 64, BATCH * HEADS), 256, 0, stream>>>(qkvb, posb, khb, vthb);
    attn_mfma<<<dim3(SEQ / 64, BATCH * HEADS), 256, 0, stream>>>(
        qkvb, khb, vthb, cntb, ybuf);
    // proj: 64x64 tiles, BK=128 -> 768 blocks (3/CU), 6 K-iters
    mgemm<64, 64, 128, 1><<<dim3(DIM / 64, NTOK / 64), 256, 0, stream>>>(
        ybuf, wproj, x1, nullptr, DIM, DIM, proj_b, x);
    ln2_kernel<<<NTOK / 4, 256, 0, stream>>>(x1, ln2_g, ln2_b, hbuf);
    mgemm<128, 128, 64, 2><<<dim3(HIDDEN / 128, NTOK / 128), 256, 0, stream>>>(
        hbuf, wfc1, a1, nullptr, HIDDEN, DIM, fc1_b, nullptr);
    // FC2 split-K=2, BK=128: z=0 -> pp (raw), z=1 -> out (+bias+resid)
    mgemm<128, 64, 128, 4><<<dim3(DIM / 64, NTOK / 128, 2), 256, 0, stream>>>(
        a1, wfc2, pp, out, DIM, HIDDEN / 2, fc2_b, x1);
    merge_kernel<<<NTOK * DIM / 1024, 256, 0, stream>>>(out, pp);
}